// Round 3
// baseline (3662.639 us; speedup 1.0000x reference)
//
#include <hip/hip_runtime.h>
#include <hip/hip_bf16.h>

// Problem constants
#define B_   64
#define T_   32
#define S_   33      // T+1 LSTM steps
#define V_   32000
#define E_   512
#define H_   1024

typedef __attribute__((ext_vector_type(8))) short  bf16x8;
typedef __attribute__((ext_vector_type(4))) float  f32x4;

// Split fp32 into hi/lo bf16 pair: x ~= hi + lo  (error ~2^-16 rel)
__device__ inline void split2(float x, unsigned short& hi, unsigned short& lo) {
    __hip_bfloat16 h = __float2bfloat16(x);
    float r = x - __bfloat162float(h);
    __hip_bfloat16 l = __float2bfloat16(r);
    hi = *reinterpret_cast<unsigned short*>(&h);
    lo = *reinterpret_cast<unsigned short*>(&l);
}

// Load 8 contiguous fp32 and split into hi/lo bf16x8 fragments (fallback path).
__device__ inline void load_f32x8_hilo(const float* __restrict__ p,
                                       bf16x8& hi, bf16x8& lo) {
    const float4* q = reinterpret_cast<const float4*>(p);
    float4 v0 = q[0], v1 = q[1];
    float f[8] = {v0.x, v0.y, v0.z, v0.w, v1.x, v1.y, v1.z, v1.w};
#pragma unroll
    for (int j = 0; j < 8; ++j) {
        unsigned short h, l; split2(f[j], h, l);
        hi[j] = (short)h; lo[j] = (short)l;
    }
}

// ---------------------------------------------------------------------------
// Kernel 1: build X[t*64+b, e]  (time-major) as hi/lo bf16.
// ---------------------------------------------------------------------------
__global__ __launch_bounds__(512) void build_x(
    const float* __restrict__ feat,   // [B,E]
    const int*   __restrict__ caps,   // [B,T] int32
    const float* __restrict__ Wemb,   // [E,V]
    const float* __restrict__ bemb,   // [E]
    unsigned short* __restrict__ Xhi,
    unsigned short* __restrict__ Xlo)
{
    int row = blockIdx.x;          // t*64 + b
    int t = row >> 6, b = row & 63;
    int e = threadIdx.x;
    float x;
    if (t == 0) {
        x = feat[b * E_ + e];
    } else {
        int cap = caps[b * T_ + (t - 1)];
        x = Wemb[(size_t)e * V_ + cap] + bemb[e];
    }
    unsigned short hi, lo; split2(x, hi, lo);
    Xhi[(size_t)row * E_ + e] = hi;
    Xlo[(size_t)row * E_ + e] = lo;
}

// ---------------------------------------------------------------------------
// Kernel 2: init LSTM state.  h -> hi/lo bf16, c fp32.  Also zeroes the
// grid-barrier counter (workspace is poison-filled by the harness).
// ---------------------------------------------------------------------------
__global__ __launch_bounds__(256) void init_state(
    const float* __restrict__ h0,
    const float* __restrict__ c0,
    unsigned short* __restrict__ hhi,
    unsigned short* __restrict__ hlo,
    float* __restrict__ c,
    unsigned int* __restrict__ bar)
{
    if (blockIdx.x == 0 && threadIdx.x == 0) *bar = 0u;
    int idx = blockIdx.x * 256 + threadIdx.x;
    unsigned short hi, lo; split2(h0[idx], hi, lo);
    hhi[idx] = hi;
    hlo[idx] = lo;
    c[idx]   = c0[idx];
}

// ---------------------------------------------------------------------------
// Kernel 2b: pre-split fp32 weights into bf16 hi/lo (once; reused 33x).
// ---------------------------------------------------------------------------
__global__ __launch_bounds__(256) void split_w(
    const float* __restrict__ src,
    unsigned short* __restrict__ hi,
    unsigned short* __restrict__ lo,
    int n4)
{
    int idx = blockIdx.x * 256 + threadIdx.x;
    int stride = gridDim.x * 256;
    for (; idx < n4; idx += stride) {
        float4 v = reinterpret_cast<const float4*>(src)[idx];
        float f[4] = {v.x, v.y, v.z, v.w};
        unsigned short h[4], l[4];
#pragma unroll
        for (int j = 0; j < 4; ++j) split2(f[j], h[j], l[j]);
        ushort4 hv; hv.x = h[0]; hv.y = h[1]; hv.z = h[2]; hv.w = h[3];
        ushort4 lv; lv.x = l[0]; lv.y = l[1]; lv.z = l[2]; lv.w = l[3];
        *reinterpret_cast<ushort4*>(hi + (size_t)idx * 4) = hv;
        *reinterpret_cast<ushort4*>(lo + (size_t)idx * 4) = lv;
    }
}

// Kernel 2c: bsum = b_ih + b_hh  (4096 elems)
__global__ __launch_bounds__(256) void bias_sum(
    const float* __restrict__ a, const float* __restrict__ b,
    float* __restrict__ s)
{
    int i = blockIdx.x * 256 + threadIdx.x;
    s[i] = a[i] + b[i];
}

// ---------------------------------------------------------------------------
// Kernel 3a (persistent, cooperative): ALL 33 LSTM steps in one launch.
// Round-2 structure (verified correct) with ONE change: cg::grid.sync()
// (~70 us/step from its deep s_sleep backoff — r2 post-mortem) replaced by a
// hand-rolled monotonic arrival-counter barrier (~2-4 us):
//   thread 0: __threadfence (release, L2 writeback of h) -> fetch_add(bar)
//   -> spin until bar >= (t+1)*gridDim.x with s_sleep(4) backoff;
//   all threads: __threadfence after (acquire, L2 inv -> fresh h).
// Monotonic counter -> no reset race. Cooperative launch guarantees
// co-residency of all 512 blocks (2/CU via __launch_bounds__(384,3)).
// ---------------------------------------------------------------------------
template<bool PRESPLIT>
__global__ __launch_bounds__(384, 3) void lstm_persist(
    const unsigned short* __restrict__ Xhi,    // [2112, 512]
    const unsigned short* __restrict__ Xlo,
    const unsigned short* __restrict__ Wihhi,  // [4096, 512]  bf16 hi
    const unsigned short* __restrict__ Wihlo,
    const unsigned short* __restrict__ Whhhi,  // [4096, 1024] bf16 hi
    const unsigned short* __restrict__ Whhlo,
    const float* __restrict__ w_ih,            // fallback fp32
    const float* __restrict__ w_hh,
    const float* __restrict__ bsum,            // [4096]
    unsigned short* __restrict__ hAhi,         // state double buffers
    unsigned short* __restrict__ hAlo,
    unsigned short* __restrict__ hBhi,
    unsigned short* __restrict__ hBlo,
    float* __restrict__ c,                     // [64, 1024] (block-local)
    float* __restrict__ out,                   // [B][S][H] fp32
    unsigned int* __restrict__ bar)            // grid barrier counter
{
    int bx   = blockIdx.x;
    int jg   = bx & 255;          // 4-col group within H
    int mgrp = bx >> 8;           // 0..1 : 32-batch group
    int wave = threadIdx.x >> 6;  // 0..5 : K-chunk
    int lane = threadIdx.x & 63;
    int lm   = lane & 15;
    int kq   = (lane >> 4) * 8;
    int tid  = threadIdx.x;
    unsigned int nblk = gridDim.x;

    // gate-interleaved weight row for this lane (g = lm>>2, jj = lm&3)
    int nrow = (lm >> 2) * H_ + jg * 4 + (lm & 3);

    bool xp  = (wave < 2);
    int lda  = xp ? E_ : H_;
    int k0   = xp ? wave * 256 : (wave - 2) * 256;
    const unsigned short* Bhi = nullptr;
    const unsigned short* Blo = nullptr;
    const float* Bf = nullptr;
    if (PRESPLIT) {
        Bhi = xp ? (Wihhi + (size_t)nrow * E_) : (Whhhi + (size_t)nrow * H_);
        Blo = xp ? (Wihlo + (size_t)nrow * E_) : (Whhlo + (size_t)nrow * H_);
    } else {
        Bf  = xp ? (w_ih + (size_t)nrow * E_)  : (w_hh + (size_t)nrow * H_);
    }

    __shared__ float pbuf[6][2][16][17];
    __shared__ float gbuf[2][16][17];
    int rbase = (lane >> 4) * 4;   // C/D: col=lane&15, row=(lane>>4)*4+r

    for (int t = 0; t < S_; ++t) {
        const unsigned short* hhi_in = (t & 1) ? hBhi : hAhi;
        const unsigned short* hlo_in = (t & 1) ? hBlo : hAlo;
        unsigned short* hhi_out = (t & 1) ? hAhi : hBhi;
        unsigned short* hlo_out = (t & 1) ? hAlo : hBlo;

        const unsigned short* Ahi = xp
            ? Xhi + (size_t)(t * 64 + mgrp * 32) * E_
            : hhi_in + (size_t)(mgrp * 32) * H_;
        const unsigned short* Alo = xp
            ? Xlo + (size_t)(t * 64 + mgrp * 32) * E_
            : hlo_in + (size_t)(mgrp * 32) * H_;

        f32x4 acc0 = f32x4{0.f, 0.f, 0.f, 0.f};
        f32x4 acc1 = f32x4{0.f, 0.f, 0.f, 0.f};

#pragma unroll
        for (int kk = 0; kk < 256; kk += 32) {
            int k = k0 + kk + kq;
            bf16x8 bhi, blo;
            if constexpr (PRESPLIT) {
                bhi = *reinterpret_cast<const bf16x8*>(Bhi + k);
                blo = *reinterpret_cast<const bf16x8*>(Blo + k);
            } else {
                load_f32x8_hilo(Bf + k, bhi, blo);
            }
            bf16x8 a0h = *reinterpret_cast<const bf16x8*>(Ahi + (size_t)lm * lda + k);
            bf16x8 a0l = *reinterpret_cast<const bf16x8*>(Alo + (size_t)lm * lda + k);
            bf16x8 a1h = *reinterpret_cast<const bf16x8*>(Ahi + (size_t)(16 + lm) * lda + k);
            bf16x8 a1l = *reinterpret_cast<const bf16x8*>(Alo + (size_t)(16 + lm) * lda + k);
            acc0 = __builtin_amdgcn_mfma_f32_16x16x32_bf16(a0h, bhi, acc0, 0, 0, 0);
            acc0 = __builtin_amdgcn_mfma_f32_16x16x32_bf16(a0l, bhi, acc0, 0, 0, 0);
            acc0 = __builtin_amdgcn_mfma_f32_16x16x32_bf16(a0h, blo, acc0, 0, 0, 0);
            acc1 = __builtin_amdgcn_mfma_f32_16x16x32_bf16(a1h, bhi, acc1, 0, 0, 0);
            acc1 = __builtin_amdgcn_mfma_f32_16x16x32_bf16(a1l, bhi, acc1, 0, 0, 0);
            acc1 = __builtin_amdgcn_mfma_f32_16x16x32_bf16(a1h, blo, acc1, 0, 0, 0);
        }

#pragma unroll
        for (int r = 0; r < 4; ++r) {
            pbuf[wave][0][rbase + r][lm] = acc0[r];
            pbuf[wave][1][rbase + r][lm] = acc1[r];
        }
        __syncthreads();

        // reduce 6 K-partials + add bias: 512 values over 384 threads
        for (int idx = tid; idx < 512; idx += 384) {
            int mt = idx >> 8, rc = idx & 255;
            int row = rc >> 4, col = rc & 15;
            float v = pbuf[0][mt][row][col] + pbuf[1][mt][row][col]
                    + pbuf[2][mt][row][col] + pbuf[3][mt][row][col]
                    + pbuf[4][mt][row][col] + pbuf[5][mt][row][col];
            int n = (col >> 2) * H_ + jg * 4 + (col & 3);
            gbuf[mt][row][col] = v + bsum[n];
        }
        __syncthreads();

        // fused pointwise: 2 mtiles x 16 batches x 4 cols = 128 outputs
        if (tid < 128) {
            int mt = tid >> 6, bl = (tid >> 2) & 15, jj = tid & 3;
            int b = mgrp * 32 + mt * 16 + bl;
            int j = jg * 4 + jj;
            float iv = gbuf[mt][bl][ 0 + jj];
            float fv = gbuf[mt][bl][ 4 + jj];
            float gv = gbuf[mt][bl][ 8 + jj];
            float ov = gbuf[mt][bl][12 + jj];
            float si = 1.f / (1.f + expf(-iv));
            float sf = 1.f / (1.f + expf(-fv));
            float so = 1.f / (1.f + expf(-ov));
            float tg = tanhf(gv);
            size_t cidx = (size_t)b * H_ + j;
            float cn = sf * c[cidx] + si * tg;
            c[cidx] = cn;
            float hn = so * tanhf(cn);
            unsigned short hi, lo; split2(hn, hi, lo);
            hhi_out[cidx] = hi;
            hlo_out[cidx] = lo;
            out[((size_t)b * S_ + t) * H_ + j] = hn;
        }

        // ---- fast grid barrier (monotonic arrival counter) ----
        __syncthreads();                       // block's h writes done
        if (tid == 0) {
            __threadfence();                   // release: writeback to coherence point
            __hip_atomic_fetch_add(bar, 1u, __ATOMIC_RELEASE, __HIP_MEMORY_SCOPE_AGENT);
            unsigned int target = (unsigned int)(t + 1) * nblk;
            while (__hip_atomic_load(bar, __ATOMIC_RELAXED, __HIP_MEMORY_SCOPE_AGENT) < target) {
                __builtin_amdgcn_s_sleep(4);
            }
        }
        __syncthreads();
        __threadfence();                       // acquire: invalidate, see fresh h
    }
}

// ---------------------------------------------------------------------------
// Kernel 3b: single-step fallback (round-1 verified) if cooperative launch
// is unavailable.
// ---------------------------------------------------------------------------
template<bool PRESPLIT>
__global__ __launch_bounds__(384) void lstm_step(
    const unsigned short* __restrict__ Xhi,
    const unsigned short* __restrict__ Xlo,
    const float* __restrict__ w_ih,
    const float* __restrict__ w_hh,
    const unsigned short* __restrict__ Wihhi,
    const unsigned short* __restrict__ Wihlo,
    const unsigned short* __restrict__ Whhhi,
    const unsigned short* __restrict__ Whhlo,
    const float* __restrict__ bsum,
    const unsigned short* __restrict__ hhi_in,
    const unsigned short* __restrict__ hlo_in,
    float* __restrict__ c,
    unsigned short* __restrict__ hhi_out,
    unsigned short* __restrict__ hlo_out,
    float* __restrict__ out,
    int t)
{
    int bx   = blockIdx.x;
    int jg   = bx & 255;
    int mgrp = bx >> 8;
    int wave = threadIdx.x >> 6;
    int lane = threadIdx.x & 63;
    int lm   = lane & 15;
    int kq   = (lane >> 4) * 8;
    int nrow = (lm >> 2) * H_ + jg * 4 + (lm & 3);

    const unsigned short *Ahi, *Alo, *Bhi = nullptr, *Blo = nullptr;
    const float* Bf = nullptr;
    int lda, k0;
    if (wave < 2) {
        k0  = wave * 256;
        lda = E_;
        if (PRESPLIT) { Bhi = Wihhi + (size_t)nrow * E_; Blo = Wihlo + (size_t)nrow * E_; }
        else          { Bf  = w_ih + (size_t)nrow * E_; }
        Ahi = Xhi + (size_t)(t * 64 + mgrp * 32) * E_;
        Alo = Xlo + (size_t)(t * 64 + mgrp * 32) * E_;
    } else {
        k0  = (wave - 2) * 256;
        lda = H_;
        if (PRESPLIT) { Bhi = Whhhi + (size_t)nrow * H_; Blo = Whhlo + (size_t)nrow * H_; }
        else          { Bf  = w_hh + (size_t)nrow * H_; }
        Ahi = hhi_in + (size_t)(mgrp * 32) * H_;
        Alo = hlo_in + (size_t)(mgrp * 32) * H_;
    }

    f32x4 acc0 = f32x4{0.f, 0.f, 0.f, 0.f};
    f32x4 acc1 = f32x4{0.f, 0.f, 0.f, 0.f};

#pragma unroll
    for (int kk = 0; kk < 256; kk += 32) {
        int k = k0 + kk + kq;
        bf16x8 bhi, blo;
        if constexpr (PRESPLIT) {
            bhi = *reinterpret_cast<const bf16x8*>(Bhi + k);
            blo = *reinterpret_cast<const bf16x8*>(Blo + k);
        } else {
            load_f32x8_hilo(Bf + k, bhi, blo);
        }
        bf16x8 a0h = *reinterpret_cast<const bf16x8*>(Ahi + (size_t)lm * lda + k);
        bf16x8 a0l = *reinterpret_cast<const bf16x8*>(Alo + (size_t)lm * lda + k);
        bf16x8 a1h = *reinterpret_cast<const bf16x8*>(Ahi + (size_t)(16 + lm) * lda + k);
        bf16x8 a1l = *reinterpret_cast<const bf16x8*>(Alo + (size_t)(16 + lm) * lda + k);
        acc0 = __builtin_amdgcn_mfma_f32_16x16x32_bf16(a0h, bhi, acc0, 0, 0, 0);
        acc0 = __builtin_amdgcn_mfma_f32_16x16x32_bf16(a0l, bhi, acc0, 0, 0, 0);
        acc0 = __builtin_amdgcn_mfma_f32_16x16x32_bf16(a0h, blo, acc0, 0, 0, 0);
        acc1 = __builtin_amdgcn_mfma_f32_16x16x32_bf16(a1h, bhi, acc1, 0, 0, 0);
        acc1 = __builtin_amdgcn_mfma_f32_16x16x32_bf16(a1l, bhi, acc1, 0, 0, 0);
        acc1 = __builtin_amdgcn_mfma_f32_16x16x32_bf16(a1h, blo, acc1, 0, 0, 0);
    }

    __shared__ float pbuf[6][2][16][17];
    __shared__ float gbuf[2][16][17];
    int rbase = (lane >> 4) * 4;
#pragma unroll
    for (int r = 0; r < 4; ++r) {
        pbuf[wave][0][rbase + r][lm] = acc0[r];
        pbuf[wave][1][rbase + r][lm] = acc1[r];
    }
    __syncthreads();

    int tid = threadIdx.x;
    for (int idx = tid; idx < 512; idx += 384) {
        int mt = idx >> 8, rc = idx & 255;
        int row = rc >> 4, col = rc & 15;
        float v = pbuf[0][mt][row][col] + pbuf[1][mt][row][col]
                + pbuf[2][mt][row][col] + pbuf[3][mt][row][col]
                + pbuf[4][mt][row][col] + pbuf[5][mt][row][col];
        int n = (col >> 2) * H_ + jg * 4 + (col & 3);
        gbuf[mt][row][col] = v + bsum[n];
    }
    __syncthreads();

    if (tid < 128) {
        int mt = tid >> 6, bl = (tid >> 2) & 15, jj = tid & 3;
        int b = mgrp * 32 + mt * 16 + bl;
        int j = jg * 4 + jj;
        float iv = gbuf[mt][bl][ 0 + jj];
        float fv = gbuf[mt][bl][ 4 + jj];
        float gv = gbuf[mt][bl][ 8 + jj];
        float ov = gbuf[mt][bl][12 + jj];
        float si = 1.f / (1.f + expf(-iv));
        float sf = 1.f / (1.f + expf(-fv));
        float so = 1.f / (1.f + expf(-ov));
        float tg = tanhf(gv);
        size_t cidx = (size_t)b * H_ + j;
        float cn = sf * c[cidx] + si * tg;
        c[cidx] = cn;
        float hn = so * tanhf(cn);
        unsigned short hi, lo; split2(hn, hi, lo);
        hhi_out[cidx] = hi;
        hlo_out[cidx] = lo;
        out[((size_t)b * S_ + t) * H_ + j] = hn;
    }
}

// ---------------------------------------------------------------------------
extern "C" void kernel_launch(void* const* d_in, const int* in_sizes, int n_in,
                              void* d_out, int out_size, void* d_ws, size_t ws_size,
                              hipStream_t stream)
{
    // Positional defaults (setup_inputs dict order)...
    const float* feat = (const float*)d_in[0];
    const int*   caps = (const int*)d_in[1];
    const float* Wemb = (const float*)d_in[2];
    const float* bemb = (const float*)d_in[3];
    const float* w_ih = (const float*)d_in[4];
    const float* w_hh = (const float*)d_in[5];
    const float* b_ih = (const float*)d_in[6];
    const float* b_hh = (const float*)d_in[7];
    const float* h0   = (const float*)d_in[8];
    const float* c0   = (const float*)d_in[9];
    int nbias = 0, nstate = 0;
    for (int i = 0; i < n_in; ++i) {
        switch (in_sizes[i]) {
            case 64 * 512:        feat = (const float*)d_in[i]; break;
            case 64 * 32:         caps = (const int*)d_in[i];   break;
            case 512 * 32000:     Wemb = (const float*)d_in[i]; break;
            case 512:             bemb = (const float*)d_in[i]; break;
            case 4096 * 512:      w_ih = (const float*)d_in[i]; break;
            case 4096 * 1024:     w_hh = (const float*)d_in[i]; break;
            case 4096:
                if (nbias++ == 0) b_ih = (const float*)d_in[i];
                else              b_hh = (const float*)d_in[i];
                break;
            case 64 * 1024:
                if (nstate++ == 0) h0 = (const float*)d_in[i];
                else               c0 = (const float*)d_in[i];
                break;
            default: break;
        }
    }
    float* out = (float*)d_out;

    // workspace layout
    char* ws = (char*)d_ws;
    unsigned short* Xhi  = (unsigned short*)ws; ws += (size_t)2112 * 512 * 2;
    unsigned short* Xlo  = (unsigned short*)ws; ws += (size_t)2112 * 512 * 2;
    unsigned short* hhiA = (unsigned short*)ws; ws += (size_t)B_ * H_ * 2;
    unsigned short* hloA = (unsigned short*)ws; ws += (size_t)B_ * H_ * 2;
    unsigned short* hhiB = (unsigned short*)ws; ws += (size_t)B_ * H_ * 2;
    unsigned short* hloB = (unsigned short*)ws; ws += (size_t)B_ * H_ * 2;
    float* cbuf          = (float*)ws;          ws += (size_t)B_ * H_ * 4;
    float* bsum          = (float*)ws;          ws += (size_t)4096 * 4;
    unsigned int* bar    = (unsigned int*)ws;   ws += 256;   // barrier counter (own line)
    unsigned short* Wihhi = (unsigned short*)ws; ws += (size_t)4096 * 512 * 2;
    unsigned short* Wihlo = (unsigned short*)ws; ws += (size_t)4096 * 512 * 2;
    unsigned short* Whhhi = (unsigned short*)ws; ws += (size_t)4096 * 1024 * 2;
    unsigned short* Whhlo = (unsigned short*)ws; ws += (size_t)4096 * 1024 * 2;
    size_t needed = (size_t)(ws - (char*)d_ws);
    bool presplit = ws_size >= needed;

    build_x<<<2112, 512, 0, stream>>>(feat, caps, Wemb, bemb, Xhi, Xlo);
    init_state<<<256, 256, 0, stream>>>(h0, c0, hhiA, hloA, cbuf, bar);
    bias_sum<<<16, 256, 0, stream>>>(b_ih, b_hh, bsum);
    if (presplit) {
        split_w<<<2048, 256, 0, stream>>>(w_ih, Wihhi, Wihlo, (4096 * 512) / 4);
        split_w<<<2048, 256, 0, stream>>>(w_hh, Whhhi, Whhlo, (4096 * 1024) / 4);
    }

    // --- persistent cooperative path ---
    void* args[] = {
        (void*)&Xhi, (void*)&Xlo,
        (void*)&Wihhi, (void*)&Wihlo, (void*)&Whhhi, (void*)&Whhlo,
        (void*)&w_ih, (void*)&w_hh,
        (void*)&bsum,
        (void*)&hhiA, (void*)&hloA, (void*)&hhiB, (void*)&hloB,
        (void*)&cbuf, (void*)&out, (void*)&bar
    };
    const void* pk = presplit ? (const void*)lstm_persist<true>
                              : (const void*)lstm_persist<false>;
    hipError_t err = hipLaunchCooperativeKernel(pk, dim3(512), dim3(384),
                                                args, 0, stream);
    if (err != hipSuccess) {
        (void)hipGetLastError();   // clear sticky error, fall back
        for (int t = 0; t < S_; ++t) {
            const unsigned short* hhi_in = (t & 1) ? hhiB : hhiA;
            const unsigned short* hlo_in = (t & 1) ? hloB : hloA;
            unsigned short* hhi_out = (t & 1) ? hhiA : hhiB;
            unsigned short* hlo_out = (t & 1) ? hloA : hloB;
            if (presplit) {
                lstm_step<true><<<512, 384, 0, stream>>>(
                    Xhi, Xlo, w_ih, w_hh, Wihhi, Wihlo, Whhhi, Whhlo, bsum,
                    hhi_in, hlo_in, cbuf, hhi_out, hlo_out, out, t);
            } else {
                lstm_step<false><<<512, 384, 0, stream>>>(
                    Xhi, Xlo, w_ih, w_hh, Wihhi, Wihlo, Whhhi, Whhlo, bsum,
                    hhi_in, hlo_in, cbuf, hhi_out, hlo_out, out, t);
            }
        }
    }
}

// Round 4
// 3036.358 us; speedup vs baseline: 1.2063x; 1.2063x over previous
//
#include <hip/hip_runtime.h>
#include <hip/hip_bf16.h>

// Problem constants
#define B_   64
#define T_   32
#define S_   33      // T+1 LSTM steps
#define V_   32000
#define E_   512
#define H_   1024

typedef __attribute__((ext_vector_type(8))) short  bf16x8;
typedef __attribute__((ext_vector_type(4))) float  f32x4;

// Split fp32 into hi/lo bf16 pair: x ~= hi + lo  (error ~2^-16 rel)
__device__ inline void split2(float x, unsigned short& hi, unsigned short& lo) {
    __hip_bfloat16 h = __float2bfloat16(x);
    float r = x - __bfloat162float(h);
    __hip_bfloat16 l = __float2bfloat16(r);
    hi = *reinterpret_cast<unsigned short*>(&h);
    lo = *reinterpret_cast<unsigned short*>(&l);
}

// Load 8 contiguous fp32 and split into hi/lo bf16x8 fragments (fallback path).
__device__ inline void load_f32x8_hilo(const float* __restrict__ p,
                                       bf16x8& hi, bf16x8& lo) {
    const float4* q = reinterpret_cast<const float4*>(p);
    float4 v0 = q[0], v1 = q[1];
    float f[8] = {v0.x, v0.y, v0.z, v0.w, v1.x, v1.y, v1.z, v1.w};
#pragma unroll
    for (int j = 0; j < 8; ++j) {
        unsigned short h, l; split2(f[j], h, l);
        hi[j] = (short)h; lo[j] = (short)l;
    }
}

// ---------------------------------------------------------------------------
// Kernel 1: build X[t*64+b, e]  (time-major) as hi/lo bf16.
// ---------------------------------------------------------------------------
__global__ __launch_bounds__(512) void build_x(
    const float* __restrict__ feat,   // [B,E]
    const int*   __restrict__ caps,   // [B,T] int32
    const float* __restrict__ Wemb,   // [E,V]
    const float* __restrict__ bemb,   // [E]
    unsigned short* __restrict__ Xhi,
    unsigned short* __restrict__ Xlo)
{
    int row = blockIdx.x;          // t*64 + b
    int t = row >> 6, b = row & 63;
    int e = threadIdx.x;
    float x;
    if (t == 0) {
        x = feat[b * E_ + e];
    } else {
        int cap = caps[b * T_ + (t - 1)];
        x = Wemb[(size_t)e * V_ + cap] + bemb[e];
    }
    unsigned short hi, lo; split2(x, hi, lo);
    Xhi[(size_t)row * E_ + e] = hi;
    Xlo[(size_t)row * E_ + e] = lo;
}

// ---------------------------------------------------------------------------
// Kernel 2: init LSTM state.  h -> hi/lo bf16, c fp32.  Also zeroes the
// barrier flags/gen (workspace is poison-filled; graph replay re-runs this).
// ---------------------------------------------------------------------------
__global__ __launch_bounds__(256) void init_state(
    const float* __restrict__ h0,
    const float* __restrict__ c0,
    unsigned short* __restrict__ hhi,
    unsigned short* __restrict__ hlo,
    float* __restrict__ c,
    unsigned int* __restrict__ flags,   // [512 * 32] (128B-padded per block)
    unsigned int* __restrict__ gen)     // [128] (gen[0], gen[64] used)
{
    int idx = blockIdx.x * 256 + threadIdx.x;
    if (idx < 512 * 32) flags[idx] = 0u;
    if (idx < 128)      gen[idx]   = 0u;
    unsigned short hi, lo; split2(h0[idx], hi, lo);
    hhi[idx] = hi;
    hlo[idx] = lo;
    c[idx]   = c0[idx];
}

// ---------------------------------------------------------------------------
// Kernel 2b: pre-split fp32 weights into bf16 hi/lo (once; reused 33x).
// ---------------------------------------------------------------------------
__global__ __launch_bounds__(256) void split_w(
    const float* __restrict__ src,
    unsigned short* __restrict__ hi,
    unsigned short* __restrict__ lo,
    int n4)
{
    int idx = blockIdx.x * 256 + threadIdx.x;
    int stride = gridDim.x * 256;
    for (; idx < n4; idx += stride) {
        float4 v = reinterpret_cast<const float4*>(src)[idx];
        float f[4] = {v.x, v.y, v.z, v.w};
        unsigned short h[4], l[4];
#pragma unroll
        for (int j = 0; j < 4; ++j) split2(f[j], h[j], l[j]);
        ushort4 hv; hv.x = h[0]; hv.y = h[1]; hv.z = h[2]; hv.w = h[3];
        ushort4 lv; lv.x = l[0]; lv.y = l[1]; lv.z = l[2]; lv.w = l[3];
        *reinterpret_cast<ushort4*>(hi + (size_t)idx * 4) = hv;
        *reinterpret_cast<ushort4*>(lo + (size_t)idx * 4) = lv;
    }
}

// Kernel 2c: bsum = b_ih + b_hh  (4096 elems)
__global__ __launch_bounds__(256) void bias_sum(
    const float* __restrict__ a, const float* __restrict__ b,
    float* __restrict__ s)
{
    int i = blockIdx.x * 256 + threadIdx.x;
    s[i] = a[i] + b[i];
}

// ---------------------------------------------------------------------------
// Kernel 3a (persistent, cooperative): ALL 33 LSTM steps in one launch.
// r2/r3 compute structure (verified). Barrier redesigned per r3 post-mortem:
// single-cacheline atomic RMW serializes 512 arrivals (~70-100us/step — both
// cg::grid.sync and the r3 counter showed it). New barrier has ZERO RMWs:
//   - each block STORES flag[bx] = t+1 to its own 128B line (parallel)
//   - checker block (one per batch-half group) polls its group's 255 flags
//     with 384 threads + __syncthreads_and, then stores gen[g] = t+1
//   - other blocks spin on gen[g] (write-once read-many line; no ping-pong)
// Barrier population split by mgrp: batches 0-31 / 32-63 are fully
// independent (h rows disjoint), so two decoupled 256-block barriers.
// Fencing identical to the passing r2/r3 pattern.
// ---------------------------------------------------------------------------
template<bool PRESPLIT>
__global__ __launch_bounds__(384, 3) void lstm_persist(
    const unsigned short* __restrict__ Xhi,    // [2112, 512]
    const unsigned short* __restrict__ Xlo,
    const unsigned short* __restrict__ Wihhi,  // [4096, 512]  bf16 hi
    const unsigned short* __restrict__ Wihlo,
    const unsigned short* __restrict__ Whhhi,  // [4096, 1024] bf16 hi
    const unsigned short* __restrict__ Whhlo,
    const float* __restrict__ w_ih,            // fallback fp32
    const float* __restrict__ w_hh,
    const float* __restrict__ bsum,            // [4096]
    unsigned short* __restrict__ hAhi,         // state double buffers
    unsigned short* __restrict__ hAlo,
    unsigned short* __restrict__ hBhi,
    unsigned short* __restrict__ hBlo,
    float* __restrict__ c,                     // [64, 1024] (block-local)
    float* __restrict__ out,                   // [B][S][H] fp32
    unsigned int* __restrict__ flags,          // [512 * 32]
    unsigned int* __restrict__ gen)            // gen[0], gen[64]
{
    int bx   = blockIdx.x;
    int jg   = bx & 255;          // 4-col group within H
    int mgrp = bx >> 8;           // 0..1 : 32-batch group
    int wave = threadIdx.x >> 6;  // 0..5 : K-chunk
    int lane = threadIdx.x & 63;
    int lm   = lane & 15;
    int kq   = (lane >> 4) * 8;
    int tid  = threadIdx.x;

    int gbase   = bx & 256;            // first block of my group (0 or 256)
    bool checker = (bx == gbase);
    unsigned int* mygen = gen + (mgrp * 64);   // 256B apart

    // gate-interleaved weight row for this lane (g = lm>>2, jj = lm&3)
    int nrow = (lm >> 2) * H_ + jg * 4 + (lm & 3);

    bool xp  = (wave < 2);
    int lda  = xp ? E_ : H_;
    int k0   = xp ? wave * 256 : (wave - 2) * 256;
    const unsigned short* Bhi = nullptr;
    const unsigned short* Blo = nullptr;
    const float* Bf = nullptr;
    if (PRESPLIT) {
        Bhi = xp ? (Wihhi + (size_t)nrow * E_) : (Whhhi + (size_t)nrow * H_);
        Blo = xp ? (Wihlo + (size_t)nrow * E_) : (Whhlo + (size_t)nrow * H_);
    } else {
        Bf  = xp ? (w_ih + (size_t)nrow * E_)  : (w_hh + (size_t)nrow * H_);
    }

    __shared__ float pbuf[6][2][16][17];
    __shared__ float gbuf[2][16][17];
    int rbase = (lane >> 4) * 4;   // C/D: col=lane&15, row=(lane>>4)*4+r

    for (int t = 0; t < S_; ++t) {
        const unsigned short* hhi_in = (t & 1) ? hBhi : hAhi;
        const unsigned short* hlo_in = (t & 1) ? hBlo : hAlo;
        unsigned short* hhi_out = (t & 1) ? hAhi : hBhi;
        unsigned short* hlo_out = (t & 1) ? hAlo : hBlo;

        const unsigned short* Ahi = xp
            ? Xhi + (size_t)(t * 64 + mgrp * 32) * E_
            : hhi_in + (size_t)(mgrp * 32) * H_;
        const unsigned short* Alo = xp
            ? Xlo + (size_t)(t * 64 + mgrp * 32) * E_
            : hlo_in + (size_t)(mgrp * 32) * H_;

        f32x4 acc0 = f32x4{0.f, 0.f, 0.f, 0.f};
        f32x4 acc1 = f32x4{0.f, 0.f, 0.f, 0.f};

#pragma unroll
        for (int kk = 0; kk < 256; kk += 32) {
            int k = k0 + kk + kq;
            bf16x8 bhi, blo;
            if constexpr (PRESPLIT) {
                bhi = *reinterpret_cast<const bf16x8*>(Bhi + k);
                blo = *reinterpret_cast<const bf16x8*>(Blo + k);
            } else {
                load_f32x8_hilo(Bf + k, bhi, blo);
            }
            bf16x8 a0h = *reinterpret_cast<const bf16x8*>(Ahi + (size_t)lm * lda + k);
            bf16x8 a0l = *reinterpret_cast<const bf16x8*>(Alo + (size_t)lm * lda + k);
            bf16x8 a1h = *reinterpret_cast<const bf16x8*>(Ahi + (size_t)(16 + lm) * lda + k);
            bf16x8 a1l = *reinterpret_cast<const bf16x8*>(Alo + (size_t)(16 + lm) * lda + k);
            acc0 = __builtin_amdgcn_mfma_f32_16x16x32_bf16(a0h, bhi, acc0, 0, 0, 0);
            acc0 = __builtin_amdgcn_mfma_f32_16x16x32_bf16(a0l, bhi, acc0, 0, 0, 0);
            acc0 = __builtin_amdgcn_mfma_f32_16x16x32_bf16(a0h, blo, acc0, 0, 0, 0);
            acc1 = __builtin_amdgcn_mfma_f32_16x16x32_bf16(a1h, bhi, acc1, 0, 0, 0);
            acc1 = __builtin_amdgcn_mfma_f32_16x16x32_bf16(a1l, bhi, acc1, 0, 0, 0);
            acc1 = __builtin_amdgcn_mfma_f32_16x16x32_bf16(a1h, blo, acc1, 0, 0, 0);
        }

#pragma unroll
        for (int r = 0; r < 4; ++r) {
            pbuf[wave][0][rbase + r][lm] = acc0[r];
            pbuf[wave][1][rbase + r][lm] = acc1[r];
        }
        __syncthreads();

        // reduce 6 K-partials + add bias: 512 values over 384 threads
        for (int idx = tid; idx < 512; idx += 384) {
            int mt = idx >> 8, rc = idx & 255;
            int row = rc >> 4, col = rc & 15;
            float v = pbuf[0][mt][row][col] + pbuf[1][mt][row][col]
                    + pbuf[2][mt][row][col] + pbuf[3][mt][row][col]
                    + pbuf[4][mt][row][col] + pbuf[5][mt][row][col];
            int n = (col >> 2) * H_ + jg * 4 + (col & 3);
            gbuf[mt][row][col] = v + bsum[n];
        }
        __syncthreads();

        // fused pointwise: 2 mtiles x 16 batches x 4 cols = 128 outputs
        if (tid < 128) {
            int mt = tid >> 6, bl = (tid >> 2) & 15, jj = tid & 3;
            int b = mgrp * 32 + mt * 16 + bl;
            int j = jg * 4 + jj;
            float iv = gbuf[mt][bl][ 0 + jj];
            float fv = gbuf[mt][bl][ 4 + jj];
            float gv = gbuf[mt][bl][ 8 + jj];
            float ov = gbuf[mt][bl][12 + jj];
            float si = 1.f / (1.f + expf(-iv));
            float sf = 1.f / (1.f + expf(-fv));
            float so = 1.f / (1.f + expf(-ov));
            float tg = tanhf(gv);
            size_t cidx = (size_t)b * H_ + j;
            float cn = sf * c[cidx] + si * tg;
            c[cidx] = cn;
            float hn = so * tanhf(cn);
            unsigned short hi, lo; split2(hn, hi, lo);
            hhi_out[cidx] = hi;
            hlo_out[cidx] = lo;
            out[((size_t)b * S_ + t) * H_ + j] = hn;
        }

        // ---- flag/checker barrier, per batch-half group (no RMWs) ----
        __syncthreads();                       // block's h writes done
        unsigned int target = (unsigned int)(t + 1);
        if (!checker) {
            if (tid == 0) {
                __threadfence();               // release: h -> coherence point
                __hip_atomic_store(&flags[(size_t)bx * 32], target,
                                   __ATOMIC_RELEASE, __HIP_MEMORY_SCOPE_AGENT);
                while (__hip_atomic_load(mygen, __ATOMIC_RELAXED,
                                         __HIP_MEMORY_SCOPE_AGENT) < target) {
                    __builtin_amdgcn_s_sleep(2);
                }
            }
        } else {
            // poll my group's other 255 flags with 255 threads in parallel
            int fi = gbase + 1 + tid;          // valid for tid < 255
            bool need = (tid < 255);
            for (;;) {
                int ok = 1;
                if (need) {
                    ok = (__hip_atomic_load(&flags[(size_t)fi * 32],
                                            __ATOMIC_RELAXED,
                                            __HIP_MEMORY_SCOPE_AGENT) >= target);
                }
                if (__syncthreads_and(ok)) break;
                __builtin_amdgcn_s_sleep(2);
            }
            if (tid == 0) {
                __threadfence();               // order: own h + observed flags -> gen
                __hip_atomic_store(mygen, target,
                                   __ATOMIC_RELEASE, __HIP_MEMORY_SCOPE_AGENT);
            }
        }
        __syncthreads();
        __threadfence();                       // acquire: invalidate, see fresh h
    }
}

// ---------------------------------------------------------------------------
// Kernel 3b: single-step fallback (round-1 verified) if cooperative launch
// is unavailable.
// ---------------------------------------------------------------------------
template<bool PRESPLIT>
__global__ __launch_bounds__(384) void lstm_step(
    const unsigned short* __restrict__ Xhi,
    const unsigned short* __restrict__ Xlo,
    const float* __restrict__ w_ih,
    const float* __restrict__ w_hh,
    const unsigned short* __restrict__ Wihhi,
    const unsigned short* __restrict__ Wihlo,
    const unsigned short* __restrict__ Whhhi,
    const unsigned short* __restrict__ Whhlo,
    const float* __restrict__ bsum,
    const unsigned short* __restrict__ hhi_in,
    const unsigned short* __restrict__ hlo_in,
    float* __restrict__ c,
    unsigned short* __restrict__ hhi_out,
    unsigned short* __restrict__ hlo_out,
    float* __restrict__ out,
    int t)
{
    int bx   = blockIdx.x;
    int jg   = bx & 255;
    int mgrp = bx >> 8;
    int wave = threadIdx.x >> 6;
    int lane = threadIdx.x & 63;
    int lm   = lane & 15;
    int kq   = (lane >> 4) * 8;
    int nrow = (lm >> 2) * H_ + jg * 4 + (lm & 3);

    const unsigned short *Ahi, *Alo, *Bhi = nullptr, *Blo = nullptr;
    const float* Bf = nullptr;
    int lda, k0;
    if (wave < 2) {
        k0  = wave * 256;
        lda = E_;
        if (PRESPLIT) { Bhi = Wihhi + (size_t)nrow * E_; Blo = Wihlo + (size_t)nrow * E_; }
        else          { Bf  = w_ih + (size_t)nrow * E_; }
        Ahi = Xhi + (size_t)(t * 64 + mgrp * 32) * E_;
        Alo = Xlo + (size_t)(t * 64 + mgrp * 32) * E_;
    } else {
        k0  = (wave - 2) * 256;
        lda = H_;
        if (PRESPLIT) { Bhi = Whhhi + (size_t)nrow * H_; Blo = Whhlo + (size_t)nrow * H_; }
        else          { Bf  = w_hh + (size_t)nrow * H_; }
        Ahi = hhi_in + (size_t)(mgrp * 32) * H_;
        Alo = hlo_in + (size_t)(mgrp * 32) * H_;
    }

    f32x4 acc0 = f32x4{0.f, 0.f, 0.f, 0.f};
    f32x4 acc1 = f32x4{0.f, 0.f, 0.f, 0.f};

#pragma unroll
    for (int kk = 0; kk < 256; kk += 32) {
        int k = k0 + kk + kq;
        bf16x8 bhi, blo;
        if constexpr (PRESPLIT) {
            bhi = *reinterpret_cast<const bf16x8*>(Bhi + k);
            blo = *reinterpret_cast<const bf16x8*>(Blo + k);
        } else {
            load_f32x8_hilo(Bf + k, bhi, blo);
        }
        bf16x8 a0h = *reinterpret_cast<const bf16x8*>(Ahi + (size_t)lm * lda + k);
        bf16x8 a0l = *reinterpret_cast<const bf16x8*>(Alo + (size_t)lm * lda + k);
        bf16x8 a1h = *reinterpret_cast<const bf16x8*>(Ahi + (size_t)(16 + lm) * lda + k);
        bf16x8 a1l = *reinterpret_cast<const bf16x8*>(Alo + (size_t)(16 + lm) * lda + k);
        acc0 = __builtin_amdgcn_mfma_f32_16x16x32_bf16(a0h, bhi, acc0, 0, 0, 0);
        acc0 = __builtin_amdgcn_mfma_f32_16x16x32_bf16(a0l, bhi, acc0, 0, 0, 0);
        acc0 = __builtin_amdgcn_mfma_f32_16x16x32_bf16(a0h, blo, acc0, 0, 0, 0);
        acc1 = __builtin_amdgcn_mfma_f32_16x16x32_bf16(a1h, bhi, acc1, 0, 0, 0);
        acc1 = __builtin_amdgcn_mfma_f32_16x16x32_bf16(a1l, bhi, acc1, 0, 0, 0);
        acc1 = __builtin_amdgcn_mfma_f32_16x16x32_bf16(a1h, blo, acc1, 0, 0, 0);
    }

    __shared__ float pbuf[6][2][16][17];
    __shared__ float gbuf[2][16][17];
    int rbase = (lane >> 4) * 4;
#pragma unroll
    for (int r = 0; r < 4; ++r) {
        pbuf[wave][0][rbase + r][lm] = acc0[r];
        pbuf[wave][1][rbase + r][lm] = acc1[r];
    }
    __syncthreads();

    int tid = threadIdx.x;
    for (int idx = tid; idx < 512; idx += 384) {
        int mt = idx >> 8, rc = idx & 255;
        int row = rc >> 4, col = rc & 15;
        float v = pbuf[0][mt][row][col] + pbuf[1][mt][row][col]
                + pbuf[2][mt][row][col] + pbuf[3][mt][row][col]
                + pbuf[4][mt][row][col] + pbuf[5][mt][row][col];
        int n = (col >> 2) * H_ + jg * 4 + (col & 3);
        gbuf[mt][row][col] = v + bsum[n];
    }
    __syncthreads();

    if (tid < 128) {
        int mt = tid >> 6, bl = (tid >> 2) & 15, jj = tid & 3;
        int b = mgrp * 32 + mt * 16 + bl;
        int j = jg * 4 + jj;
        float iv = gbuf[mt][bl][ 0 + jj];
        float fv = gbuf[mt][bl][ 4 + jj];
        float gv = gbuf[mt][bl][ 8 + jj];
        float ov = gbuf[mt][bl][12 + jj];
        float si = 1.f / (1.f + expf(-iv));
        float sf = 1.f / (1.f + expf(-fv));
        float so = 1.f / (1.f + expf(-ov));
        float tg = tanhf(gv);
        size_t cidx = (size_t)b * H_ + j;
        float cn = sf * c[cidx] + si * tg;
        c[cidx] = cn;
        float hn = so * tanhf(cn);
        unsigned short hi, lo; split2(hn, hi, lo);
        hhi_out[cidx] = hi;
        hlo_out[cidx] = lo;
        out[((size_t)b * S_ + t) * H_ + j] = hn;
    }
}

// ---------------------------------------------------------------------------
extern "C" void kernel_launch(void* const* d_in, const int* in_sizes, int n_in,
                              void* d_out, int out_size, void* d_ws, size_t ws_size,
                              hipStream_t stream)
{
    // Positional defaults (setup_inputs dict order)...
    const float* feat = (const float*)d_in[0];
    const int*   caps = (const int*)d_in[1];
    const float* Wemb = (const float*)d_in[2];
    const float* bemb = (const float*)d_in[3];
    const float* w_ih = (const float*)d_in[4];
    const float* w_hh = (const float*)d_in[5];
    const float* b_ih = (const float*)d_in[6];
    const float* b_hh = (const float*)d_in[7];
    const float* h0   = (const float*)d_in[8];
    const float* c0   = (const float*)d_in[9];
    int nbias = 0, nstate = 0;
    for (int i = 0; i < n_in; ++i) {
        switch (in_sizes[i]) {
            case 64 * 512:        feat = (const float*)d_in[i]; break;
            case 64 * 32:         caps = (const int*)d_in[i];   break;
            case 512 * 32000:     Wemb = (const float*)d_in[i]; break;
            case 512:             bemb = (const float*)d_in[i]; break;
            case 4096 * 512:      w_ih = (const float*)d_in[i]; break;
            case 4096 * 1024:     w_hh = (const float*)d_in[i]; break;
            case 4096:
                if (nbias++ == 0) b_ih = (const float*)d_in[i];
                else              b_hh = (const float*)d_in[i];
                break;
            case 64 * 1024:
                if (nstate++ == 0) h0 = (const float*)d_in[i];
                else               c0 = (const float*)d_in[i];
                break;
            default: break;
        }
    }
    float* out = (float*)d_out;

    // workspace layout
    char* ws = (char*)d_ws;
    unsigned short* Xhi  = (unsigned short*)ws; ws += (size_t)2112 * 512 * 2;
    unsigned short* Xlo  = (unsigned short*)ws; ws += (size_t)2112 * 512 * 2;
    unsigned short* hhiA = (unsigned short*)ws; ws += (size_t)B_ * H_ * 2;
    unsigned short* hloA = (unsigned short*)ws; ws += (size_t)B_ * H_ * 2;
    unsigned short* hhiB = (unsigned short*)ws; ws += (size_t)B_ * H_ * 2;
    unsigned short* hloB = (unsigned short*)ws; ws += (size_t)B_ * H_ * 2;
    float* cbuf          = (float*)ws;          ws += (size_t)B_ * H_ * 4;
    float* bsum          = (float*)ws;          ws += (size_t)4096 * 4;
    unsigned int* flags  = (unsigned int*)ws;   ws += (size_t)512 * 32 * 4;  // 128B/block
    unsigned int* gen    = (unsigned int*)ws;   ws += (size_t)128 * 4;       // gen[0], gen[64]
    unsigned short* Wihhi = (unsigned short*)ws; ws += (size_t)4096 * 512 * 2;
    unsigned short* Wihlo = (unsigned short*)ws; ws += (size_t)4096 * 512 * 2;
    unsigned short* Whhhi = (unsigned short*)ws; ws += (size_t)4096 * 1024 * 2;
    unsigned short* Whhlo = (unsigned short*)ws; ws += (size_t)4096 * 1024 * 2;
    size_t needed = (size_t)(ws - (char*)d_ws);
    bool presplit = ws_size >= needed;

    build_x<<<2112, 512, 0, stream>>>(feat, caps, Wemb, bemb, Xhi, Xlo);
    init_state<<<256, 256, 0, stream>>>(h0, c0, hhiA, hloA, cbuf, flags, gen);
    bias_sum<<<16, 256, 0, stream>>>(b_ih, b_hh, bsum);
    if (presplit) {
        split_w<<<2048, 256, 0, stream>>>(w_ih, Wihhi, Wihlo, (4096 * 512) / 4);
        split_w<<<2048, 256, 0, stream>>>(w_hh, Whhhi, Whhlo, (4096 * 1024) / 4);
    }

    // --- persistent cooperative path ---
    void* args[] = {
        (void*)&Xhi, (void*)&Xlo,
        (void*)&Wihhi, (void*)&Wihlo, (void*)&Whhhi, (void*)&Whhlo,
        (void*)&w_ih, (void*)&w_hh,
        (void*)&bsum,
        (void*)&hhiA, (void*)&hloA, (void*)&hhiB, (void*)&hloB,
        (void*)&cbuf, (void*)&out, (void*)&flags, (void*)&gen
    };
    const void* pk = presplit ? (const void*)lstm_persist<true>
                              : (const void*)lstm_persist<false>;
    hipError_t err = hipLaunchCooperativeKernel(pk, dim3(512), dim3(384),
                                                args, 0, stream);
    if (err != hipSuccess) {
        (void)hipGetLastError();   // clear sticky error, fall back
        for (int t = 0; t < S_; ++t) {
            const unsigned short* hhi_in = (t & 1) ? hhiB : hhiA;
            const unsigned short* hlo_in = (t & 1) ? hloB : hloA;
            unsigned short* hhi_out = (t & 1) ? hhiA : hhiB;
            unsigned short* hlo_out = (t & 1) ? hloA : hloB;
            if (presplit) {
                lstm_step<true><<<512, 384, 0, stream>>>(
                    Xhi, Xlo, w_ih, w_hh, Wihhi, Wihlo, Whhhi, Whhlo, bsum,
                    hhi_in, hlo_in, cbuf, hhi_out, hlo_out, out, t);
            } else {
                lstm_step<false><<<512, 384, 0, stream>>>(
                    Xhi, Xlo, w_ih, w_hh, Wihhi, Wihlo, Whhhi, Whhlo, bsum,
                    hhi_in, hlo_in, cbuf, hhi_out, hlo_out, out, t);
            }
        }
    }
}

// Round 5
// 967.551 us; speedup vs baseline: 3.7855x; 3.1382x over previous
//
#include <hip/hip_runtime.h>
#include <hip/hip_bf16.h>

// Problem constants
#define B_   64
#define T_   32
#define S_   33      // T+1 LSTM steps
#define V_   32000
#define E_   512
#define H_   1024

typedef __attribute__((ext_vector_type(8))) short  bf16x8;
typedef __attribute__((ext_vector_type(4))) float  f32x4;

// Split fp32 into hi/lo bf16 pair: x ~= hi + lo  (error ~2^-16 rel)
__device__ inline void split2(float x, unsigned short& hi, unsigned short& lo) {
    __hip_bfloat16 h = __float2bfloat16(x);
    float r = x - __bfloat162float(h);
    __hip_bfloat16 l = __float2bfloat16(r);
    hi = *reinterpret_cast<unsigned short*>(&h);
    lo = *reinterpret_cast<unsigned short*>(&l);
}

// Load 8 contiguous fp32 and split into hi/lo bf16x8 fragments (fallback path).
__device__ inline void load_f32x8_hilo(const float* __restrict__ p,
                                       bf16x8& hi, bf16x8& lo) {
    const float4* q = reinterpret_cast<const float4*>(p);
    float4 v0 = q[0], v1 = q[1];
    float f[8] = {v0.x, v0.y, v0.z, v0.w, v1.x, v1.y, v1.z, v1.w};
#pragma unroll
    for (int j = 0; j < 8; ++j) {
        unsigned short h, l; split2(f[j], h, l);
        hi[j] = (short)h; lo[j] = (short)l;
    }
}

// Load 8 packed-h uints (hi | lo<<16) via relaxed AGENT atomics (sc-flagged:
// bypass non-coherent L1/L2, served by memory-side Infinity Cache) and unpack.
__device__ inline void load_hpack8(const unsigned int* p, bf16x8& hi, bf16x8& lo) {
#pragma unroll
    for (int q = 0; q < 4; ++q) {
        unsigned long long v = __hip_atomic_load(
            reinterpret_cast<const unsigned long long*>(p) + q,
            __ATOMIC_RELAXED, __HIP_MEMORY_SCOPE_AGENT);
        unsigned int w0 = (unsigned int)v;
        unsigned int w1 = (unsigned int)(v >> 32);
        hi[2 * q]     = (short)(w0 & 0xffffu);
        lo[2 * q]     = (short)(w0 >> 16);
        hi[2 * q + 1] = (short)(w1 & 0xffffu);
        lo[2 * q + 1] = (short)(w1 >> 16);
    }
}

// ---------------------------------------------------------------------------
// Kernel 1: build X[t*64+b, e]  (time-major) as hi/lo bf16.
// ---------------------------------------------------------------------------
__global__ __launch_bounds__(512) void build_x(
    const float* __restrict__ feat,   // [B,E]
    const int*   __restrict__ caps,   // [B,T] int32
    const float* __restrict__ Wemb,   // [E,V]
    const float* __restrict__ bemb,   // [E]
    unsigned short* __restrict__ Xhi,
    unsigned short* __restrict__ Xlo)
{
    int row = blockIdx.x;          // t*64 + b
    int t = row >> 6, b = row & 63;
    int e = threadIdx.x;
    float x;
    if (t == 0) {
        x = feat[b * E_ + e];
    } else {
        int cap = caps[b * T_ + (t - 1)];
        x = Wemb[(size_t)e * V_ + cap] + bemb[e];
    }
    unsigned short hi, lo; split2(x, hi, lo);
    Xhi[(size_t)row * E_ + e] = hi;
    Xlo[(size_t)row * E_ + e] = lo;
}

// ---------------------------------------------------------------------------
// Kernel 2: init LSTM state.  h -> packed uint (hi | lo<<16), c fp32.
// Also zeroes barrier flags/gen (workspace is poison-filled each iteration).
// ---------------------------------------------------------------------------
__global__ __launch_bounds__(256) void init_state(
    const float* __restrict__ h0,
    const float* __restrict__ c0,
    unsigned int* __restrict__ hpk,
    float* __restrict__ c,
    unsigned int* __restrict__ flags,   // [512 * 32] (128B-padded per block)
    unsigned int* __restrict__ gen)     // [128] (gen[0], gen[64] used)
{
    int idx = blockIdx.x * 256 + threadIdx.x;
    if (idx < 512 * 32) flags[idx] = 0u;
    if (idx < 128)      gen[idx]   = 0u;
    unsigned short hi, lo; split2(h0[idx], hi, lo);
    hpk[idx] = (unsigned int)hi | ((unsigned int)lo << 16);
    c[idx]   = c0[idx];
}

// ---------------------------------------------------------------------------
// Kernel 2b: pre-split fp32 weights into bf16 hi/lo (once; reused 33x).
// ---------------------------------------------------------------------------
__global__ __launch_bounds__(256) void split_w(
    const float* __restrict__ src,
    unsigned short* __restrict__ hi,
    unsigned short* __restrict__ lo,
    int n4)
{
    int idx = blockIdx.x * 256 + threadIdx.x;
    int stride = gridDim.x * 256;
    for (; idx < n4; idx += stride) {
        float4 v = reinterpret_cast<const float4*>(src)[idx];
        float f[4] = {v.x, v.y, v.z, v.w};
        unsigned short h[4], l[4];
#pragma unroll
        for (int j = 0; j < 4; ++j) split2(f[j], h[j], l[j]);
        ushort4 hv; hv.x = h[0]; hv.y = h[1]; hv.z = h[2]; hv.w = h[3];
        ushort4 lv; lv.x = l[0]; lv.y = l[1]; lv.z = l[2]; lv.w = l[3];
        *reinterpret_cast<ushort4*>(hi + (size_t)idx * 4) = hv;
        *reinterpret_cast<ushort4*>(lo + (size_t)idx * 4) = lv;
    }
}

// Kernel 2c: bsum = b_ih + b_hh  (4096 elems)
__global__ __launch_bounds__(256) void bias_sum(
    const float* __restrict__ a, const float* __restrict__ b,
    float* __restrict__ s)
{
    int i = blockIdx.x * 256 + threadIdx.x;
    s[i] = a[i] + b[i];
}

// ---------------------------------------------------------------------------
// Kernel 3a (persistent, cooperative): ALL 33 LSTM steps in one launch.
// r4 compute/barrier structure (verified) minus ALL fences (r4 post-mortem:
// 6144 per-step wbl2+inv ops were the ~80us/step cost and killed L2 weight
// residency). Cross-block h exchange is now fence-free:
//   - h packed as uint (hi|lo<<16); producers store with relaxed AGENT
//     atomics (sc-flagged -> coherence point / Infinity Cache, no L2 dirt)
//   - __syncthreads() drains vmcnt(0) per wave (compiler-guaranteed) ->
//     stores are device-visible before tid0's relaxed flag store
//   - consumers read h with relaxed AGENT atomic loads (bypass stale L1/L2)
//   - weights/X/bias/c remain normally cached: L2-resident all 33 steps
// Flag/checker barrier per batch-half group (no RMWs, no fences).
// ---------------------------------------------------------------------------
template<bool PRESPLIT>
__global__ __launch_bounds__(384, 3) void lstm_persist(
    const unsigned short* __restrict__ Xhi,    // [2112, 512]
    const unsigned short* __restrict__ Xlo,
    const unsigned short* __restrict__ Wihhi,  // [4096, 512]  bf16 hi
    const unsigned short* __restrict__ Wihlo,
    const unsigned short* __restrict__ Whhhi,  // [4096, 1024] bf16 hi
    const unsigned short* __restrict__ Whhlo,
    const float* __restrict__ w_ih,            // fallback fp32
    const float* __restrict__ w_hh,
    const float* __restrict__ bsum,            // [4096]
    unsigned int* __restrict__ hpkA,           // packed h double buffers
    unsigned int* __restrict__ hpkB,
    float* __restrict__ c,                     // [64, 1024] (block-local)
    float* __restrict__ out,                   // [B][S][H] fp32
    unsigned int* __restrict__ flags,          // [512 * 32]
    unsigned int* __restrict__ gen)            // gen[0], gen[64]
{
    int bx   = blockIdx.x;
    int jg   = bx & 255;          // 4-col group within H
    int mgrp = bx >> 8;           // 0..1 : 32-batch group
    int wave = threadIdx.x >> 6;  // 0..5 : K-chunk
    int lane = threadIdx.x & 63;
    int lm   = lane & 15;
    int kq   = (lane >> 4) * 8;
    int tid  = threadIdx.x;

    int gbase    = bx & 256;           // first block of my group (0 or 256)
    bool checker = (bx == gbase);
    unsigned int* mygen = gen + (mgrp * 64);   // 256B apart

    // gate-interleaved weight row for this lane (g = lm>>2, jj = lm&3)
    int nrow = (lm >> 2) * H_ + jg * 4 + (lm & 3);

    bool xp  = (wave < 2);
    int k0   = xp ? wave * 256 : (wave - 2) * 256;
    const unsigned short* Bhi = nullptr;
    const unsigned short* Blo = nullptr;
    const float* Bf = nullptr;
    if (PRESPLIT) {
        Bhi = xp ? (Wihhi + (size_t)nrow * E_) : (Whhhi + (size_t)nrow * H_);
        Blo = xp ? (Wihlo + (size_t)nrow * E_) : (Whhlo + (size_t)nrow * H_);
    } else {
        Bf  = xp ? (w_ih + (size_t)nrow * E_)  : (w_hh + (size_t)nrow * H_);
    }

    __shared__ float pbuf[6][2][16][17];
    __shared__ float gbuf[2][16][17];
    int rbase = (lane >> 4) * 4;   // C/D: col=lane&15, row=(lane>>4)*4+r

    for (int t = 0; t < S_; ++t) {
        const unsigned int* hpk_in = (t & 1) ? hpkB : hpkA;
        unsigned int*      hpk_out = (t & 1) ? hpkA : hpkB;

        // per-step A operand bases
        const unsigned short* Axhi = Xhi + (size_t)(t * 64 + mgrp * 32) * E_;
        const unsigned short* Axlo = Xlo + (size_t)(t * 64 + mgrp * 32) * E_;
        const unsigned int* hrow0 = hpk_in + (size_t)(mgrp * 32 + lm) * H_;
        const unsigned int* hrow1 = hpk_in + (size_t)(mgrp * 32 + 16 + lm) * H_;

        f32x4 acc0 = f32x4{0.f, 0.f, 0.f, 0.f};
        f32x4 acc1 = f32x4{0.f, 0.f, 0.f, 0.f};

#pragma unroll
        for (int kk = 0; kk < 256; kk += 32) {
            int k = k0 + kk + kq;
            bf16x8 bhi, blo;
            if constexpr (PRESPLIT) {
                bhi = *reinterpret_cast<const bf16x8*>(Bhi + k);
                blo = *reinterpret_cast<const bf16x8*>(Blo + k);
            } else {
                load_f32x8_hilo(Bf + k, bhi, blo);
            }
            bf16x8 a0h, a0l, a1h, a1l;
            if (xp) {
                a0h = *reinterpret_cast<const bf16x8*>(Axhi + (size_t)lm * E_ + k);
                a0l = *reinterpret_cast<const bf16x8*>(Axlo + (size_t)lm * E_ + k);
                a1h = *reinterpret_cast<const bf16x8*>(Axhi + (size_t)(16 + lm) * E_ + k);
                a1l = *reinterpret_cast<const bf16x8*>(Axlo + (size_t)(16 + lm) * E_ + k);
            } else {
                load_hpack8(hrow0 + k, a0h, a0l);
                load_hpack8(hrow1 + k, a1h, a1l);
            }
            acc0 = __builtin_amdgcn_mfma_f32_16x16x32_bf16(a0h, bhi, acc0, 0, 0, 0);
            acc0 = __builtin_amdgcn_mfma_f32_16x16x32_bf16(a0l, bhi, acc0, 0, 0, 0);
            acc0 = __builtin_amdgcn_mfma_f32_16x16x32_bf16(a0h, blo, acc0, 0, 0, 0);
            acc1 = __builtin_amdgcn_mfma_f32_16x16x32_bf16(a1h, bhi, acc1, 0, 0, 0);
            acc1 = __builtin_amdgcn_mfma_f32_16x16x32_bf16(a1l, bhi, acc1, 0, 0, 0);
            acc1 = __builtin_amdgcn_mfma_f32_16x16x32_bf16(a1h, blo, acc1, 0, 0, 0);
        }

#pragma unroll
        for (int r = 0; r < 4; ++r) {
            pbuf[wave][0][rbase + r][lm] = acc0[r];
            pbuf[wave][1][rbase + r][lm] = acc1[r];
        }
        __syncthreads();

        // reduce 6 K-partials + add bias: 512 values over 384 threads
        for (int idx = tid; idx < 512; idx += 384) {
            int mt = idx >> 8, rc = idx & 255;
            int row = rc >> 4, col = rc & 15;
            float v = pbuf[0][mt][row][col] + pbuf[1][mt][row][col]
                    + pbuf[2][mt][row][col] + pbuf[3][mt][row][col]
                    + pbuf[4][mt][row][col] + pbuf[5][mt][row][col];
            int n = (col >> 2) * H_ + jg * 4 + (col & 3);
            gbuf[mt][row][col] = v + bsum[n];
        }
        __syncthreads();

        // fused pointwise: 2 mtiles x 16 batches x 4 cols = 128 outputs
        if (tid < 128) {
            int mt = tid >> 6, bl = (tid >> 2) & 15, jj = tid & 3;
            int b = mgrp * 32 + mt * 16 + bl;
            int j = jg * 4 + jj;
            float iv = gbuf[mt][bl][ 0 + jj];
            float fv = gbuf[mt][bl][ 4 + jj];
            float gv = gbuf[mt][bl][ 8 + jj];
            float ov = gbuf[mt][bl][12 + jj];
            float si = 1.f / (1.f + expf(-iv));
            float sf = 1.f / (1.f + expf(-fv));
            float so = 1.f / (1.f + expf(-ov));
            float tg = tanhf(gv);
            size_t cidx = (size_t)b * H_ + j;
            float cn = sf * c[cidx] + si * tg;
            c[cidx] = cn;
            float hn = so * tanhf(cn);
            unsigned short hi, lo; split2(hn, hi, lo);
            // device-scope packed store -> coherence point (no fence needed)
            __hip_atomic_store(&hpk_out[cidx],
                               (unsigned int)hi | ((unsigned int)lo << 16),
                               __ATOMIC_RELAXED, __HIP_MEMORY_SCOPE_AGENT);
            out[((size_t)b * S_ + t) * H_ + j] = hn;
        }

        // ---- flag/checker barrier, per batch-half group (no fences) ----
        __syncthreads();   // drains vmcnt(0) on every wave -> h stores visible
        unsigned int target = (unsigned int)(t + 1);
        if (!checker) {
            if (tid == 0) {
                __hip_atomic_store(&flags[(size_t)bx * 32], target,
                                   __ATOMIC_RELAXED, __HIP_MEMORY_SCOPE_AGENT);
                while (__hip_atomic_load(mygen, __ATOMIC_RELAXED,
                                         __HIP_MEMORY_SCOPE_AGENT) < target) {
                    __builtin_amdgcn_s_sleep(2);
                }
            }
        } else {
            // poll my group's other 255 flags with 255 threads in parallel
            int fi = gbase + 1 + tid;          // valid for tid < 255
            bool need = (tid < 255);
            for (;;) {
                int ok = 1;
                if (need) {
                    ok = (__hip_atomic_load(&flags[(size_t)fi * 32],
                                            __ATOMIC_RELAXED,
                                            __HIP_MEMORY_SCOPE_AGENT) >= target);
                }
                if (__syncthreads_and(ok)) break;
                __builtin_amdgcn_s_sleep(2);
            }
            if (tid == 0) {
                __hip_atomic_store(mygen, target,
                                   __ATOMIC_RELAXED, __HIP_MEMORY_SCOPE_AGENT);
            }
        }
        __syncthreads();   // all threads held until tid0's spin exit
    }
}

// ---------------------------------------------------------------------------
// Kernel 3b: single-step fallback if cooperative launch is unavailable
// (kernel boundaries provide visibility; same packed-h format).
// ---------------------------------------------------------------------------
template<bool PRESPLIT>
__global__ __launch_bounds__(384) void lstm_step(
    const unsigned short* __restrict__ Xhi,
    const unsigned short* __restrict__ Xlo,
    const float* __restrict__ w_ih,
    const float* __restrict__ w_hh,
    const unsigned short* __restrict__ Wihhi,
    const unsigned short* __restrict__ Wihlo,
    const unsigned short* __restrict__ Whhhi,
    const unsigned short* __restrict__ Whhlo,
    const float* __restrict__ bsum,
    const unsigned int* __restrict__ hpk_in,
    float* __restrict__ c,
    unsigned int* __restrict__ hpk_out,
    float* __restrict__ out,
    int t)
{
    int bx   = blockIdx.x;
    int jg   = bx & 255;
    int mgrp = bx >> 8;
    int wave = threadIdx.x >> 6;
    int lane = threadIdx.x & 63;
    int lm   = lane & 15;
    int kq   = (lane >> 4) * 8;
    int nrow = (lm >> 2) * H_ + jg * 4 + (lm & 3);

    bool xp  = (wave < 2);
    int k0   = xp ? wave * 256 : (wave - 2) * 256;
    const unsigned short* Bhi = nullptr;
    const unsigned short* Blo = nullptr;
    const float* Bf = nullptr;
    if (PRESPLIT) {
        Bhi = xp ? (Wihhi + (size_t)nrow * E_) : (Whhhi + (size_t)nrow * H_);
        Blo = xp ? (Wihlo + (size_t)nrow * E_) : (Whhlo + (size_t)nrow * H_);
    } else {
        Bf  = xp ? (w_ih + (size_t)nrow * E_)  : (w_hh + (size_t)nrow * H_);
    }
    const unsigned short* Axhi = Xhi + (size_t)(t * 64 + mgrp * 32) * E_;
    const unsigned short* Axlo = Xlo + (size_t)(t * 64 + mgrp * 32) * E_;
    const unsigned int* hrow0 = hpk_in + (size_t)(mgrp * 32 + lm) * H_;
    const unsigned int* hrow1 = hpk_in + (size_t)(mgrp * 32 + 16 + lm) * H_;

    f32x4 acc0 = f32x4{0.f, 0.f, 0.f, 0.f};
    f32x4 acc1 = f32x4{0.f, 0.f, 0.f, 0.f};

#pragma unroll
    for (int kk = 0; kk < 256; kk += 32) {
        int k = k0 + kk + kq;
        bf16x8 bhi, blo;
        if constexpr (PRESPLIT) {
            bhi = *reinterpret_cast<const bf16x8*>(Bhi + k);
            blo = *reinterpret_cast<const bf16x8*>(Blo + k);
        } else {
            load_f32x8_hilo(Bf + k, bhi, blo);
        }
        bf16x8 a0h, a0l, a1h, a1l;
        if (xp) {
            a0h = *reinterpret_cast<const bf16x8*>(Axhi + (size_t)lm * E_ + k);
            a0l = *reinterpret_cast<const bf16x8*>(Axlo + (size_t)lm * E_ + k);
            a1h = *reinterpret_cast<const bf16x8*>(Axhi + (size_t)(16 + lm) * E_ + k);
            a1l = *reinterpret_cast<const bf16x8*>(Axlo + (size_t)(16 + lm) * E_ + k);
        } else {
            load_hpack8(hrow0 + k, a0h, a0l);
            load_hpack8(hrow1 + k, a1h, a1l);
        }
        acc0 = __builtin_amdgcn_mfma_f32_16x16x32_bf16(a0h, bhi, acc0, 0, 0, 0);
        acc0 = __builtin_amdgcn_mfma_f32_16x16x32_bf16(a0l, bhi, acc0, 0, 0, 0);
        acc0 = __builtin_amdgcn_mfma_f32_16x16x32_bf16(a0h, blo, acc0, 0, 0, 0);
        acc1 = __builtin_amdgcn_mfma_f32_16x16x32_bf16(a1h, bhi, acc1, 0, 0, 0);
        acc1 = __builtin_amdgcn_mfma_f32_16x16x32_bf16(a1l, bhi, acc1, 0, 0, 0);
        acc1 = __builtin_amdgcn_mfma_f32_16x16x32_bf16(a1h, blo, acc1, 0, 0, 0);
    }

    __shared__ float pbuf[6][2][16][17];
    __shared__ float gbuf[2][16][17];
    int rbase = (lane >> 4) * 4;
#pragma unroll
    for (int r = 0; r < 4; ++r) {
        pbuf[wave][0][rbase + r][lm] = acc0[r];
        pbuf[wave][1][rbase + r][lm] = acc1[r];
    }
    __syncthreads();

    int tid = threadIdx.x;
    for (int idx = tid; idx < 512; idx += 384) {
        int mt = idx >> 8, rc = idx & 255;
        int row = rc >> 4, col = rc & 15;
        float v = pbuf[0][mt][row][col] + pbuf[1][mt][row][col]
                + pbuf[2][mt][row][col] + pbuf[3][mt][row][col]
                + pbuf[4][mt][row][col] + pbuf[5][mt][row][col];
        int n = (col >> 2) * H_ + jg * 4 + (col & 3);
        gbuf[mt][row][col] = v + bsum[n];
    }
    __syncthreads();

    if (tid < 128) {
        int mt = tid >> 6, bl = (tid >> 2) & 15, jj = tid & 3;
        int b = mgrp * 32 + mt * 16 + bl;
        int j = jg * 4 + jj;
        float iv = gbuf[mt][bl][ 0 + jj];
        float fv = gbuf[mt][bl][ 4 + jj];
        float gv = gbuf[mt][bl][ 8 + jj];
        float ov = gbuf[mt][bl][12 + jj];
        float si = 1.f / (1.f + expf(-iv));
        float sf = 1.f / (1.f + expf(-fv));
        float so = 1.f / (1.f + expf(-ov));
        float tg = tanhf(gv);
        size_t cidx = (size_t)b * H_ + j;
        float cn = sf * c[cidx] + si * tg;
        c[cidx] = cn;
        float hn = so * tanhf(cn);
        unsigned short hi, lo; split2(hn, hi, lo);
        hpk_out[cidx] = (unsigned int)hi | ((unsigned int)lo << 16);
        out[((size_t)b * S_ + t) * H_ + j] = hn;
    }
}

// ---------------------------------------------------------------------------
extern "C" void kernel_launch(void* const* d_in, const int* in_sizes, int n_in,
                              void* d_out, int out_size, void* d_ws, size_t ws_size,
                              hipStream_t stream)
{
    // Positional defaults (setup_inputs dict order)...
    const float* feat = (const float*)d_in[0];
    const int*   caps = (const int*)d_in[1];
    const float* Wemb = (const float*)d_in[2];
    const float* bemb = (const float*)d_in[3];
    const float* w_ih = (const float*)d_in[4];
    const float* w_hh = (const float*)d_in[5];
    const float* b_ih = (const float*)d_in[6];
    const float* b_hh = (const float*)d_in[7];
    const float* h0   = (const float*)d_in[8];
    const float* c0   = (const float*)d_in[9];
    int nbias = 0, nstate = 0;
    for (int i = 0; i < n_in; ++i) {
        switch (in_sizes[i]) {
            case 64 * 512:        feat = (const float*)d_in[i]; break;
            case 64 * 32:         caps = (const int*)d_in[i];   break;
            case 512 * 32000:     Wemb = (const float*)d_in[i]; break;
            case 512:             bemb = (const float*)d_in[i]; break;
            case 4096 * 512:      w_ih = (const float*)d_in[i]; break;
            case 4096 * 1024:     w_hh = (const float*)d_in[i]; break;
            case 4096:
                if (nbias++ == 0) b_ih = (const float*)d_in[i];
                else              b_hh = (const float*)d_in[i];
                break;
            case 64 * 1024:
                if (nstate++ == 0) h0 = (const float*)d_in[i];
                else               c0 = (const float*)d_in[i];
                break;
            default: break;
        }
    }
    float* out = (float*)d_out;

    // workspace layout
    char* ws = (char*)d_ws;
    unsigned short* Xhi  = (unsigned short*)ws; ws += (size_t)2112 * 512 * 2;
    unsigned short* Xlo  = (unsigned short*)ws; ws += (size_t)2112 * 512 * 2;
    unsigned int* hpkA   = (unsigned int*)ws;   ws += (size_t)B_ * H_ * 4;
    unsigned int* hpkB   = (unsigned int*)ws;   ws += (size_t)B_ * H_ * 4;
    float* cbuf          = (float*)ws;          ws += (size_t)B_ * H_ * 4;
    float* bsum          = (float*)ws;          ws += (size_t)4096 * 4;
    unsigned int* flags  = (unsigned int*)ws;   ws += (size_t)512 * 32 * 4;  // 128B/block
    unsigned int* gen    = (unsigned int*)ws;   ws += (size_t)128 * 4;       // gen[0], gen[64]
    unsigned short* Wihhi = (unsigned short*)ws; ws += (size_t)4096 * 512 * 2;
    unsigned short* Wihlo = (unsigned short*)ws; ws += (size_t)4096 * 512 * 2;
    unsigned short* Whhhi = (unsigned short*)ws; ws += (size_t)4096 * 1024 * 2;
    unsigned short* Whhlo = (unsigned short*)ws; ws += (size_t)4096 * 1024 * 2;
    size_t needed = (size_t)(ws - (char*)d_ws);
    bool presplit = ws_size >= needed;

    build_x<<<2112, 512, 0, stream>>>(feat, caps, Wemb, bemb, Xhi, Xlo);
    init_state<<<256, 256, 0, stream>>>(h0, c0, hpkA, cbuf, flags, gen);
    bias_sum<<<16, 256, 0, stream>>>(b_ih, b_hh, bsum);
    if (presplit) {
        split_w<<<2048, 256, 0, stream>>>(w_ih, Wihhi, Wihlo, (4096 * 512) / 4);
        split_w<<<2048, 256, 0, stream>>>(w_hh, Whhhi, Whhlo, (4096 * 1024) / 4);
    }

    // --- persistent cooperative path ---
    void* args[] = {
        (void*)&Xhi, (void*)&Xlo,
        (void*)&Wihhi, (void*)&Wihlo, (void*)&Whhhi, (void*)&Whhlo,
        (void*)&w_ih, (void*)&w_hh,
        (void*)&bsum,
        (void*)&hpkA, (void*)&hpkB,
        (void*)&cbuf, (void*)&out, (void*)&flags, (void*)&gen
    };
    const void* pk = presplit ? (const void*)lstm_persist<true>
                              : (const void*)lstm_persist<false>;
    hipError_t err = hipLaunchCooperativeKernel(pk, dim3(512), dim3(384),
                                                args, 0, stream);
    if (err != hipSuccess) {
        (void)hipGetLastError();   // clear sticky error, fall back
        for (int t = 0; t < S_; ++t) {
            const unsigned int* hin = (t & 1) ? hpkB : hpkA;
            unsigned int*      hout = (t & 1) ? hpkA : hpkB;
            if (presplit) {
                lstm_step<true><<<512, 384, 0, stream>>>(
                    Xhi, Xlo, w_ih, w_hh, Wihhi, Wihlo, Whhhi, Whhlo, bsum,
                    hin, cbuf, hout, out, t);
            } else {
                lstm_step<false><<<512, 384, 0, stream>>>(
                    Xhi, Xlo, w_ih, w_hh, Wihhi, Wihlo, Whhhi, Whhlo, bsum,
                    hin, cbuf, hout, out, t);
            }
        }
    }
}

// Round 6
// 736.457 us; speedup vs baseline: 4.9733x; 1.3138x over previous
//
#include <hip/hip_runtime.h>
#include <hip/hip_bf16.h>

// Problem constants
#define B_   64
#define T_   32
#define S_   33      // T+1 LSTM steps
#define V_   32000
#define E_   512
#define H_   1024
#define HB_  (B_ * H_)   // one h buffer, in uints (packed hi|lo)

typedef __attribute__((ext_vector_type(8))) short  bf16x8;
typedef __attribute__((ext_vector_type(4))) float  f32x4;

// Split fp32 into hi/lo bf16 pair: x ~= hi + lo  (error ~2^-16 rel)
__device__ inline void split2(float x, unsigned short& hi, unsigned short& lo) {
    __hip_bfloat16 h = __float2bfloat16(x);
    float r = x - __bfloat162float(h);
    __hip_bfloat16 l = __float2bfloat16(r);
    hi = *reinterpret_cast<unsigned short*>(&h);
    lo = *reinterpret_cast<unsigned short*>(&l);
}

// Load 8 contiguous fp32 and split into hi/lo bf16x8 fragments (fallback path).
__device__ inline void load_f32x8_hilo(const float* __restrict__ p,
                                       bf16x8& hi, bf16x8& lo) {
    const float4* q = reinterpret_cast<const float4*>(p);
    float4 v0 = q[0], v1 = q[1];
    float f[8] = {v0.x, v0.y, v0.z, v0.w, v1.x, v1.y, v1.z, v1.w};
#pragma unroll
    for (int j = 0; j < 8; ++j) {
        unsigned short h, l; split2(f[j], h, l);
        hi[j] = (short)h; lo[j] = (short)l;
    }
}

// Load 8 packed-h uints (hi | lo<<16) with NORMAL cached loads and unpack.
// Safe because hseq buffers are write-once: no XCD L2 can hold a stale copy
// (lines are first touched after the producing step's barrier).
__device__ inline void load_hpk8(const unsigned int* __restrict__ p,
                                 bf16x8& hi, bf16x8& lo) {
    uint4 v0 = *reinterpret_cast<const uint4*>(p);
    uint4 v1 = *reinterpret_cast<const uint4*>(p + 4);
    unsigned int w[8] = {v0.x, v0.y, v0.z, v0.w, v1.x, v1.y, v1.z, v1.w};
#pragma unroll
    for (int j = 0; j < 8; ++j) {
        hi[j] = (short)(w[j] & 0xffffu);
        lo[j] = (short)(w[j] >> 16);
    }
}

// ---------------------------------------------------------------------------
// Kernel 1: build X[t*64+b, e]  (time-major) as hi/lo bf16.
// ---------------------------------------------------------------------------
__global__ __launch_bounds__(512) void build_x(
    const float* __restrict__ feat,   // [B,E]
    const int*   __restrict__ caps,   // [B,T] int32
    const float* __restrict__ Wemb,   // [E,V]
    const float* __restrict__ bemb,   // [E]
    unsigned short* __restrict__ Xhi,
    unsigned short* __restrict__ Xlo)
{
    int row = blockIdx.x;          // t*64 + b
    int t = row >> 6, b = row & 63;
    int e = threadIdx.x;
    float x;
    if (t == 0) {
        x = feat[b * E_ + e];
    } else {
        int cap = caps[b * T_ + (t - 1)];
        x = Wemb[(size_t)e * V_ + cap] + bemb[e];
    }
    unsigned short hi, lo; split2(x, hi, lo);
    Xhi[(size_t)row * E_ + e] = hi;
    Xlo[(size_t)row * E_ + e] = lo;
}

// ---------------------------------------------------------------------------
// Kernel 2: init LSTM state.  h -> packed uint (hi | lo<<16) into hseq[0],
// c fp32.  Also zeroes barrier flags/gen (workspace is poison-filled).
// ---------------------------------------------------------------------------
__global__ __launch_bounds__(256) void init_state(
    const float* __restrict__ h0,
    const float* __restrict__ c0,
    unsigned int* __restrict__ hseq0,
    float* __restrict__ c,
    unsigned int* __restrict__ flags,   // [512 * 32] (128B-padded per block)
    unsigned int* __restrict__ gen)     // [128] (gen[0], gen[64] used)
{
    int idx = blockIdx.x * 256 + threadIdx.x;
    if (idx < 512 * 32) flags[idx] = 0u;
    if (idx < 128)      gen[idx]   = 0u;
    unsigned short hi, lo; split2(h0[idx], hi, lo);
    hseq0[idx] = (unsigned int)hi | ((unsigned int)lo << 16);
    c[idx]   = c0[idx];
}

// ---------------------------------------------------------------------------
// Kernel 2b: pre-split fp32 weights into bf16 hi/lo (once; reused 33x).
// ---------------------------------------------------------------------------
__global__ __launch_bounds__(256) void split_w(
    const float* __restrict__ src,
    unsigned short* __restrict__ hi,
    unsigned short* __restrict__ lo,
    int n4)
{
    int idx = blockIdx.x * 256 + threadIdx.x;
    int stride = gridDim.x * 256;
    for (; idx < n4; idx += stride) {
        float4 v = reinterpret_cast<const float4*>(src)[idx];
        float f[4] = {v.x, v.y, v.z, v.w};
        unsigned short h[4], l[4];
#pragma unroll
        for (int j = 0; j < 4; ++j) split2(f[j], h[j], l[j]);
        ushort4 hv; hv.x = h[0]; hv.y = h[1]; hv.z = h[2]; hv.w = h[3];
        ushort4 lv; lv.x = l[0]; lv.y = l[1]; lv.z = l[2]; lv.w = l[3];
        *reinterpret_cast<ushort4*>(hi + (size_t)idx * 4) = hv;
        *reinterpret_cast<ushort4*>(lo + (size_t)idx * 4) = lv;
    }
}

// Kernel 2c: bsum = b_ih + b_hh  (4096 elems)
__global__ __launch_bounds__(256) void bias_sum(
    const float* __restrict__ a, const float* __restrict__ b,
    float* __restrict__ s)
{
    int i = blockIdx.x * 256 + threadIdx.x;
    s[i] = a[i] + b[i];
}

// ---------------------------------------------------------------------------
// Kernel 3a (persistent, cooperative): ALL 33 LSTM steps in one launch.
// r5 structure (verified) with ONE change per the r5 post-mortem: h-consumer
// loads were sc-flagged atomics bypassing L1/L2 -> 64 MB/step of uncached
// per-lane IC transactions (~17us/step). Now the h sequence is WRITE-ONCE:
// hseq[t] read at step t (normal cached loads; lines first touched after the
// producing barrier -> no stale copy possible), hseq[t+1] written with
// relaxed AGENT sc-stores (straight to IC; vmcnt-drained by __syncthreads
// before the flag store -- the r5-verified release pattern). Weights/X/bias/c
// stay normally cached and L2-resident across all 33 steps.
// Flag/checker barrier per batch-half group (no RMWs, no fences) unchanged.
// ---------------------------------------------------------------------------
template<bool PRESPLIT>
__global__ __launch_bounds__(384, 3) void lstm_persist(
    const unsigned short* __restrict__ Xhi,    // [2112, 512]
    const unsigned short* __restrict__ Xlo,
    const unsigned short* __restrict__ Wihhi,  // [4096, 512]  bf16 hi
    const unsigned short* __restrict__ Wihlo,
    const unsigned short* __restrict__ Whhhi,  // [4096, 1024] bf16 hi
    const unsigned short* __restrict__ Whhlo,
    const float* __restrict__ w_ih,            // fallback fp32
    const float* __restrict__ w_hh,
    const float* __restrict__ bsum,            // [4096]
    unsigned int* __restrict__ hseq,           // [34][64*1024] write-once
    float* __restrict__ c,                     // [64, 1024] (block-local)
    float* __restrict__ out,                   // [B][S][H] fp32
    unsigned int* __restrict__ flags,          // [512 * 32]
    unsigned int* __restrict__ gen)            // gen[0], gen[64]
{
    int bx   = blockIdx.x;
    int jg   = bx & 255;          // 4-col group within H
    int mgrp = bx >> 8;           // 0..1 : 32-batch group
    int wave = threadIdx.x >> 6;  // 0..5 : K-chunk
    int lane = threadIdx.x & 63;
    int lm   = lane & 15;
    int kq   = (lane >> 4) * 8;
    int tid  = threadIdx.x;

    int gbase    = bx & 256;           // first block of my group (0 or 256)
    bool checker = (bx == gbase);
    unsigned int* mygen = gen + (mgrp * 64);   // 256B apart

    // gate-interleaved weight row for this lane (g = lm>>2, jj = lm&3)
    int nrow = (lm >> 2) * H_ + jg * 4 + (lm & 3);

    bool xp  = (wave < 2);
    int k0   = xp ? wave * 256 : (wave - 2) * 256;
    const unsigned short* Bhi = nullptr;
    const unsigned short* Blo = nullptr;
    const float* Bf = nullptr;
    if (PRESPLIT) {
        Bhi = xp ? (Wihhi + (size_t)nrow * E_) : (Whhhi + (size_t)nrow * H_);
        Blo = xp ? (Wihlo + (size_t)nrow * E_) : (Whhlo + (size_t)nrow * H_);
    } else {
        Bf  = xp ? (w_ih + (size_t)nrow * E_)  : (w_hh + (size_t)nrow * H_);
    }

    __shared__ float pbuf[6][2][16][17];
    __shared__ float gbuf[2][16][17];
    int rbase = (lane >> 4) * 4;   // C/D: col=lane&15, row=(lane>>4)*4+r

    for (int t = 0; t < S_; ++t) {
        const unsigned int* hpk_in = hseq + (size_t)t * HB_;
        unsigned int*      hpk_out = hseq + (size_t)(t + 1) * HB_;

        // per-step A operand bases
        const unsigned short* Axhi = Xhi + (size_t)(t * 64 + mgrp * 32) * E_;
        const unsigned short* Axlo = Xlo + (size_t)(t * 64 + mgrp * 32) * E_;
        const unsigned int* hrow0 = hpk_in + (size_t)(mgrp * 32 + lm) * H_;
        const unsigned int* hrow1 = hpk_in + (size_t)(mgrp * 32 + 16 + lm) * H_;

        f32x4 acc0 = f32x4{0.f, 0.f, 0.f, 0.f};
        f32x4 acc1 = f32x4{0.f, 0.f, 0.f, 0.f};

#pragma unroll
        for (int kk = 0; kk < 256; kk += 32) {
            int k = k0 + kk + kq;
            bf16x8 bhi, blo;
            if constexpr (PRESPLIT) {
                bhi = *reinterpret_cast<const bf16x8*>(Bhi + k);
                blo = *reinterpret_cast<const bf16x8*>(Blo + k);
            } else {
                load_f32x8_hilo(Bf + k, bhi, blo);
            }
            bf16x8 a0h, a0l, a1h, a1l;
            if (xp) {
                a0h = *reinterpret_cast<const bf16x8*>(Axhi + (size_t)lm * E_ + k);
                a0l = *reinterpret_cast<const bf16x8*>(Axlo + (size_t)lm * E_ + k);
                a1h = *reinterpret_cast<const bf16x8*>(Axhi + (size_t)(16 + lm) * E_ + k);
                a1l = *reinterpret_cast<const bf16x8*>(Axlo + (size_t)(16 + lm) * E_ + k);
            } else {
                load_hpk8(hrow0 + k, a0h, a0l);
                load_hpk8(hrow1 + k, a1h, a1l);
            }
            acc0 = __builtin_amdgcn_mfma_f32_16x16x32_bf16(a0h, bhi, acc0, 0, 0, 0);
            acc0 = __builtin_amdgcn_mfma_f32_16x16x32_bf16(a0l, bhi, acc0, 0, 0, 0);
            acc0 = __builtin_amdgcn_mfma_f32_16x16x32_bf16(a0h, blo, acc0, 0, 0, 0);
            acc1 = __builtin_amdgcn_mfma_f32_16x16x32_bf16(a1h, bhi, acc1, 0, 0, 0);
            acc1 = __builtin_amdgcn_mfma_f32_16x16x32_bf16(a1l, bhi, acc1, 0, 0, 0);
            acc1 = __builtin_amdgcn_mfma_f32_16x16x32_bf16(a1h, blo, acc1, 0, 0, 0);
        }

#pragma unroll
        for (int r = 0; r < 4; ++r) {
            pbuf[wave][0][rbase + r][lm] = acc0[r];
            pbuf[wave][1][rbase + r][lm] = acc1[r];
        }
        __syncthreads();

        // reduce 6 K-partials + add bias: 512 values over 384 threads
        for (int idx = tid; idx < 512; idx += 384) {
            int mt = idx >> 8, rc = idx & 255;
            int row = rc >> 4, col = rc & 15;
            float v = pbuf[0][mt][row][col] + pbuf[1][mt][row][col]
                    + pbuf[2][mt][row][col] + pbuf[3][mt][row][col]
                    + pbuf[4][mt][row][col] + pbuf[5][mt][row][col];
            int n = (col >> 2) * H_ + jg * 4 + (col & 3);
            gbuf[mt][row][col] = v + bsum[n];
        }
        __syncthreads();

        // fused pointwise: 2 mtiles x 16 batches x 4 cols = 128 outputs
        if (tid < 128) {
            int mt = tid >> 6, bl = (tid >> 2) & 15, jj = tid & 3;
            int b = mgrp * 32 + mt * 16 + bl;
            int j = jg * 4 + jj;
            float iv = gbuf[mt][bl][ 0 + jj];
            float fv = gbuf[mt][bl][ 4 + jj];
            float gv = gbuf[mt][bl][ 8 + jj];
            float ov = gbuf[mt][bl][12 + jj];
            float si = 1.f / (1.f + expf(-iv));
            float sf = 1.f / (1.f + expf(-fv));
            float so = 1.f / (1.f + expf(-ov));
            float tg = tanhf(gv);
            size_t cidx = (size_t)b * H_ + j;
            float cn = sf * c[cidx] + si * tg;
            c[cidx] = cn;
            float hn = so * tanhf(cn);
            unsigned short hi, lo; split2(hn, hi, lo);
            // device-scope packed store -> coherence point (IC); no fence
            __hip_atomic_store(&hpk_out[cidx],
                               (unsigned int)hi | ((unsigned int)lo << 16),
                               __ATOMIC_RELAXED, __HIP_MEMORY_SCOPE_AGENT);
            out[((size_t)b * S_ + t) * H_ + j] = hn;
        }

        // ---- flag/checker barrier, per batch-half group (no fences) ----
        __syncthreads();   // drains vmcnt(0) on every wave -> h stores visible
        unsigned int target = (unsigned int)(t + 1);
        if (!checker) {
            if (tid == 0) {
                __hip_atomic_store(&flags[(size_t)bx * 32], target,
                                   __ATOMIC_RELAXED, __HIP_MEMORY_SCOPE_AGENT);
                while (__hip_atomic_load(mygen, __ATOMIC_RELAXED,
                                         __HIP_MEMORY_SCOPE_AGENT) < target) {
                    __builtin_amdgcn_s_sleep(2);
                }
            }
        } else {
            // poll my group's other 255 flags with 255 threads in parallel
            int fi = gbase + 1 + tid;          // valid for tid < 255
            bool need = (tid < 255);
            for (;;) {
                int ok = 1;
                if (need) {
                    ok = (__hip_atomic_load(&flags[(size_t)fi * 32],
                                            __ATOMIC_RELAXED,
                                            __HIP_MEMORY_SCOPE_AGENT) >= target);
                }
                if (__syncthreads_and(ok)) break;
                __builtin_amdgcn_s_sleep(2);
            }
            if (tid == 0) {
                __hip_atomic_store(mygen, target,
                                   __ATOMIC_RELAXED, __HIP_MEMORY_SCOPE_AGENT);
            }
        }
        __syncthreads();   // all threads held until tid0's spin exit
    }
}

// ---------------------------------------------------------------------------
// Kernel 3b: single-step fallback if cooperative launch is unavailable
// (kernel boundaries provide visibility; same write-once hseq format).
// ---------------------------------------------------------------------------
template<bool PRESPLIT>
__global__ __launch_bounds__(384) void lstm_step(
    const unsigned short* __restrict__ Xhi,
    const unsigned short* __restrict__ Xlo,
    const float* __restrict__ w_ih,
    const float* __restrict__ w_hh,
    const unsigned short* __restrict__ Wihhi,
    const unsigned short* __restrict__ Wihlo,
    const unsigned short* __restrict__ Whhhi,
    const unsigned short* __restrict__ Whhlo,
    const float* __restrict__ bsum,
    const unsigned int* __restrict__ hpk_in,
    float* __restrict__ c,
    unsigned int* __restrict__ hpk_out,
    float* __restrict__ out,
    int t)
{
    int bx   = blockIdx.x;
    int jg   = bx & 255;
    int mgrp = bx >> 8;
    int wave = threadIdx.x >> 6;
    int lane = threadIdx.x & 63;
    int lm   = lane & 15;
    int kq   = (lane >> 4) * 8;
    int nrow = (lm >> 2) * H_ + jg * 4 + (lm & 3);

    bool xp  = (wave < 2);
    int k0   = xp ? wave * 256 : (wave - 2) * 256;
    const unsigned short* Bhi = nullptr;
    const unsigned short* Blo = nullptr;
    const float* Bf = nullptr;
    if (PRESPLIT) {
        Bhi = xp ? (Wihhi + (size_t)nrow * E_) : (Whhhi + (size_t)nrow * H_);
        Blo = xp ? (Wihlo + (size_t)nrow * E_) : (Whhlo + (size_t)nrow * H_);
    } else {
        Bf  = xp ? (w_ih + (size_t)nrow * E_)  : (w_hh + (size_t)nrow * H_);
    }
    const unsigned short* Axhi = Xhi + (size_t)(t * 64 + mgrp * 32) * E_;
    const unsigned short* Axlo = Xlo + (size_t)(t * 64 + mgrp * 32) * E_;
    const unsigned int* hrow0 = hpk_in + (size_t)(mgrp * 32 + lm) * H_;
    const unsigned int* hrow1 = hpk_in + (size_t)(mgrp * 32 + 16 + lm) * H_;

    f32x4 acc0 = f32x4{0.f, 0.f, 0.f, 0.f};
    f32x4 acc1 = f32x4{0.f, 0.f, 0.f, 0.f};

#pragma unroll
    for (int kk = 0; kk < 256; kk += 32) {
        int k = k0 + kk + kq;
        bf16x8 bhi, blo;
        if constexpr (PRESPLIT) {
            bhi = *reinterpret_cast<const bf16x8*>(Bhi + k);
            blo = *reinterpret_cast<const bf16x8*>(Blo + k);
        } else {
            load_f32x8_hilo(Bf + k, bhi, blo);
        }
        bf16x8 a0h, a0l, a1h, a1l;
        if (xp) {
            a0h = *reinterpret_cast<const bf16x8*>(Axhi + (size_t)lm * E_ + k);
            a0l = *reinterpret_cast<const bf16x8*>(Axlo + (size_t)lm * E_ + k);
            a1h = *reinterpret_cast<const bf16x8*>(Axhi + (size_t)(16 + lm) * E_ + k);
            a1l = *reinterpret_cast<const bf16x8*>(Axlo + (size_t)(16 + lm) * E_ + k);
        } else {
            load_hpk8(hrow0 + k, a0h, a0l);
            load_hpk8(hrow1 + k, a1h, a1l);
        }
        acc0 = __builtin_amdgcn_mfma_f32_16x16x32_bf16(a0h, bhi, acc0, 0, 0, 0);
        acc0 = __builtin_amdgcn_mfma_f32_16x16x32_bf16(a0l, bhi, acc0, 0, 0, 0);
        acc0 = __builtin_amdgcn_mfma_f32_16x16x32_bf16(a0h, blo, acc0, 0, 0, 0);
        acc1 = __builtin_amdgcn_mfma_f32_16x16x32_bf16(a1h, bhi, acc1, 0, 0, 0);
        acc1 = __builtin_amdgcn_mfma_f32_16x16x32_bf16(a1l, bhi, acc1, 0, 0, 0);
        acc1 = __builtin_amdgcn_mfma_f32_16x16x32_bf16(a1h, blo, acc1, 0, 0, 0);
    }

    __shared__ float pbuf[6][2][16][17];
    __shared__ float gbuf[2][16][17];
    int rbase = (lane >> 4) * 4;
#pragma unroll
    for (int r = 0; r < 4; ++r) {
        pbuf[wave][0][rbase + r][lm] = acc0[r];
        pbuf[wave][1][rbase + r][lm] = acc1[r];
    }
    __syncthreads();

    int tid = threadIdx.x;
    for (int idx = tid; idx < 512; idx += 384) {
        int mt = idx >> 8, rc = idx & 255;
        int row = rc >> 4, col = rc & 15;
        float v = pbuf[0][mt][row][col] + pbuf[1][mt][row][col]
                + pbuf[2][mt][row][col] + pbuf[3][mt][row][col]
                + pbuf[4][mt][row][col] + pbuf[5][mt][row][col];
        int n = (col >> 2) * H_ + jg * 4 + (col & 3);
        gbuf[mt][row][col] = v + bsum[n];
    }
    __syncthreads();

    if (tid < 128) {
        int mt = tid >> 6, bl = (tid >> 2) & 15, jj = tid & 3;
        int b = mgrp * 32 + mt * 16 + bl;
        int j = jg * 4 + jj;
        float iv = gbuf[mt][bl][ 0 + jj];
        float fv = gbuf[mt][bl][ 4 + jj];
        float gv = gbuf[mt][bl][ 8 + jj];
        float ov = gbuf[mt][bl][12 + jj];
        float si = 1.f / (1.f + expf(-iv));
        float sf = 1.f / (1.f + expf(-fv));
        float so = 1.f / (1.f + expf(-ov));
        float tg = tanhf(gv);
        size_t cidx = (size_t)b * H_ + j;
        float cn = sf * c[cidx] + si * tg;
        c[cidx] = cn;
        float hn = so * tanhf(cn);
        unsigned short hi, lo; split2(hn, hi, lo);
        hpk_out[cidx] = (unsigned int)hi | ((unsigned int)lo << 16);
        out[((size_t)b * S_ + t) * H_ + j] = hn;
    }
}

// ---------------------------------------------------------------------------
extern "C" void kernel_launch(void* const* d_in, const int* in_sizes, int n_in,
                              void* d_out, int out_size, void* d_ws, size_t ws_size,
                              hipStream_t stream)
{
    // Positional defaults (setup_inputs dict order)...
    const float* feat = (const float*)d_in[0];
    const int*   caps = (const int*)d_in[1];
    const float* Wemb = (const float*)d_in[2];
    const float* bemb = (const float*)d_in[3];
    const float* w_ih = (const float*)d_in[4];
    const float* w_hh = (const float*)d_in[5];
    const float* b_ih = (const float*)d_in[6];
    const float* b_hh = (const float*)d_in[7];
    const float* h0   = (const float*)d_in[8];
    const float* c0   = (const float*)d_in[9];
    int nbias = 0, nstate = 0;
    for (int i = 0; i < n_in; ++i) {
        switch (in_sizes[i]) {
            case 64 * 512:        feat = (const float*)d_in[i]; break;
            case 64 * 32:         caps = (const int*)d_in[i];   break;
            case 512 * 32000:     Wemb = (const float*)d_in[i]; break;
            case 512:             bemb = (const float*)d_in[i]; break;
            case 4096 * 512:      w_ih = (const float*)d_in[i]; break;
            case 4096 * 1024:     w_hh = (const float*)d_in[i]; break;
            case 4096:
                if (nbias++ == 0) b_ih = (const float*)d_in[i];
                else              b_hh = (const float*)d_in[i];
                break;
            case 64 * 1024:
                if (nstate++ == 0) h0 = (const float*)d_in[i];
                else               c0 = (const float*)d_in[i];
                break;
            default: break;
        }
    }
    float* out = (float*)d_out;

    // workspace layout
    char* ws = (char*)d_ws;
    unsigned short* Xhi  = (unsigned short*)ws; ws += (size_t)2112 * 512 * 2;
    unsigned short* Xlo  = (unsigned short*)ws; ws += (size_t)2112 * 512 * 2;
    unsigned int* hseq   = (unsigned int*)ws;   ws += (size_t)(S_ + 1) * HB_ * 4; // 8.7MB write-once
    float* cbuf          = (float*)ws;          ws += (size_t)B_ * H_ * 4;
    float* bsum          = (float*)ws;          ws += (size_t)4096 * 4;
    unsigned int* flags  = (unsigned int*)ws;   ws += (size_t)512 * 32 * 4;  // 128B/block
    unsigned int* gen    = (unsigned int*)ws;   ws += (size_t)128 * 4;       // gen[0], gen[64]
    unsigned short* Wihhi = (unsigned short*)ws; ws += (size_t)4096 * 512 * 2;
    unsigned short* Wihlo = (unsigned short*)ws; ws += (size_t)4096 * 512 * 2;
    unsigned short* Whhhi = (unsigned short*)ws; ws += (size_t)4096 * 1024 * 2;
    unsigned short* Whhlo = (unsigned short*)ws; ws += (size_t)4096 * 1024 * 2;
    size_t needed = (size_t)(ws - (char*)d_ws);
    bool presplit = ws_size >= needed;

    build_x<<<2112, 512, 0, stream>>>(feat, caps, Wemb, bemb, Xhi, Xlo);
    init_state<<<256, 256, 0, stream>>>(h0, c0, hseq, cbuf, flags, gen);
    bias_sum<<<16, 256, 0, stream>>>(b_ih, b_hh, bsum);
    if (presplit) {
        split_w<<<2048, 256, 0, stream>>>(w_ih, Wihhi, Wihlo, (4096 * 512) / 4);
        split_w<<<2048, 256, 0, stream>>>(w_hh, Whhhi, Whhlo, (4096 * 1024) / 4);
    }

    // --- persistent cooperative path ---
    void* args[] = {
        (void*)&Xhi, (void*)&Xlo,
        (void*)&Wihhi, (void*)&Wihlo, (void*)&Whhhi, (void*)&Whhlo,
        (void*)&w_ih, (void*)&w_hh,
        (void*)&bsum,
        (void*)&hseq,
        (void*)&cbuf, (void*)&out, (void*)&flags, (void*)&gen
    };
    const void* pk = presplit ? (const void*)lstm_persist<true>
                              : (const void*)lstm_persist<false>;
    hipError_t err = hipLaunchCooperativeKernel(pk, dim3(512), dim3(384),
                                                args, 0, stream);
    if (err != hipSuccess) {
        (void)hipGetLastError();   // clear sticky error, fall back
        for (int t = 0; t < S_; ++t) {
            const unsigned int* hin = hseq + (size_t)t * HB_;
            unsigned int*      hout = hseq + (size_t)(t + 1) * HB_;
            if (presplit) {
                lstm_step<true><<<512, 384, 0, stream>>>(
                    Xhi, Xlo, w_ih, w_hh, Wihhi, Wihlo, Whhhi, Whhlo, bsum,
                    hin, cbuf, hout, out, t);
            } else {
                lstm_step<false><<<512, 384, 0, stream>>>(
                    Xhi, Xlo, w_ih, w_hh, Wihhi, Wihlo, Whhhi, Whhlo, bsum,
                    hin, cbuf, hout, out, t);
            }
        }
    }
}

// Round 7
// 720.262 us; speedup vs baseline: 5.0852x; 1.0225x over previous
//
#include <hip/hip_runtime.h>
#include <hip/hip_bf16.h>

// Problem constants
#define B_   64
#define T_   32
#define S_   33      // T+1 LSTM steps
#define V_   32000
#define E_   512
#define H_   1024
#define HB_  (B_ * H_)   // one h buffer, in uints (packed hi|lo)
#define NG_  4096        // 4 gates * H

typedef __attribute__((ext_vector_type(8))) short  bf16x8;
typedef __attribute__((ext_vector_type(4))) float  f32x4;

// Split fp32 into hi/lo bf16 pair: x ~= hi + lo  (error ~2^-16 rel)
__device__ inline void split2(float x, unsigned short& hi, unsigned short& lo) {
    __hip_bfloat16 h = __float2bfloat16(x);
    float r = x - __bfloat162float(h);
    __hip_bfloat16 l = __float2bfloat16(r);
    hi = *reinterpret_cast<unsigned short*>(&h);
    lo = *reinterpret_cast<unsigned short*>(&l);
}

// Load 8 contiguous fp32 and split into hi/lo bf16x8 fragments (fallback path).
__device__ inline void load_f32x8_hilo(const float* __restrict__ p,
                                       bf16x8& hi, bf16x8& lo) {
    const float4* q = reinterpret_cast<const float4*>(p);
    float4 v0 = q[0], v1 = q[1];
    float f[8] = {v0.x, v0.y, v0.z, v0.w, v1.x, v1.y, v1.z, v1.w};
#pragma unroll
    for (int j = 0; j < 8; ++j) {
        unsigned short h, l; split2(f[j], h, l);
        hi[j] = (short)h; lo[j] = (short)l;
    }
}

// Load 8 packed-h uints (hi | lo<<16) with NORMAL cached loads and unpack.
// Safe: hseq buffers are write-once (r6-verified).
__device__ inline void load_hpk8(const unsigned int* __restrict__ p,
                                 bf16x8& hi, bf16x8& lo) {
    uint4 v0 = *reinterpret_cast<const uint4*>(p);
    uint4 v1 = *reinterpret_cast<const uint4*>(p + 4);
    unsigned int w[8] = {v0.x, v0.y, v0.z, v0.w, v1.x, v1.y, v1.z, v1.w};
#pragma unroll
    for (int j = 0; j < 8; ++j) {
        hi[j] = (short)(w[j] & 0xffffu);
        lo[j] = (short)(w[j] >> 16);
    }
}

// ---------------------------------------------------------------------------
// Kernel 1: build X[t*64+b, e]  (time-major) as hi/lo bf16.
// ---------------------------------------------------------------------------
__global__ __launch_bounds__(512) void build_x(
    const float* __restrict__ feat,   // [B,E]
    const int*   __restrict__ caps,   // [B,T] int32
    const float* __restrict__ Wemb,   // [E,V]
    const float* __restrict__ bemb,   // [E]
    unsigned short* __restrict__ Xhi,
    unsigned short* __restrict__ Xlo)
{
    int row = blockIdx.x;          // t*64 + b
    int t = row >> 6, b = row & 63;
    int e = threadIdx.x;
    float x;
    if (t == 0) {
        x = feat[b * E_ + e];
    } else {
        int cap = caps[b * T_ + (t - 1)];
        x = Wemb[(size_t)e * V_ + cap] + bemb[e];
    }
    unsigned short hi, lo; split2(x, hi, lo);
    Xhi[(size_t)row * E_ + e] = hi;
    Xlo[(size_t)row * E_ + e] = lo;
}

// ---------------------------------------------------------------------------
// Kernel 2: init LSTM state.  h -> packed uint (hi | lo<<16) into hseq[0],
// c fp32.  Also zeroes barrier flags/gen (workspace is poison-filled).
// ---------------------------------------------------------------------------
__global__ __launch_bounds__(256) void init_state(
    const float* __restrict__ h0,
    const float* __restrict__ c0,
    unsigned int* __restrict__ hseq0,
    float* __restrict__ c,
    unsigned int* __restrict__ flags,   // [512 * 32] (128B-padded per block)
    unsigned int* __restrict__ gen)     // [128] (gen[0], gen[64] used)
{
    int idx = blockIdx.x * 256 + threadIdx.x;
    if (idx < 512 * 32) flags[idx] = 0u;
    if (idx < 128)      gen[idx]   = 0u;
    unsigned short hi, lo; split2(h0[idx], hi, lo);
    hseq0[idx] = (unsigned int)hi | ((unsigned int)lo << 16);
    c[idx]   = c0[idx];
}

// ---------------------------------------------------------------------------
// Kernel 2b: pre-split fp32 weights into bf16 hi/lo (once).
// ---------------------------------------------------------------------------
__global__ __launch_bounds__(256) void split_w(
    const float* __restrict__ src,
    unsigned short* __restrict__ hi,
    unsigned short* __restrict__ lo,
    int n4)
{
    int idx = blockIdx.x * 256 + threadIdx.x;
    int stride = gridDim.x * 256;
    for (; idx < n4; idx += stride) {
        float4 v = reinterpret_cast<const float4*>(src)[idx];
        float f[4] = {v.x, v.y, v.z, v.w};
        unsigned short h[4], l[4];
#pragma unroll
        for (int j = 0; j < 4; ++j) split2(f[j], h[j], l[j]);
        ushort4 hv; hv.x = h[0]; hv.y = h[1]; hv.z = h[2]; hv.w = h[3];
        ushort4 lv; lv.x = l[0]; lv.y = l[1]; lv.z = l[2]; lv.w = l[3];
        *reinterpret_cast<ushort4*>(hi + (size_t)idx * 4) = hv;
        *reinterpret_cast<ushort4*>(lo + (size_t)idx * 4) = lv;
    }
}

// Kernel 2c: bsum = b_ih + b_hh  (4096 elems)
__global__ __launch_bounds__(256) void bias_sum(
    const float* __restrict__ a, const float* __restrict__ b,
    float* __restrict__ s)
{
    int i = blockIdx.x * 256 + threadIdx.x;
    s[i] = a[i] + b[i];
}

// ---------------------------------------------------------------------------
// Kernel 2d: Gxi = X @ w_ih^T + bsum, hoisted out of the recurrence
// (time-invariant: no h dependency). M=2112, N=4096, K=512.
// Output in GATE-INTERLEAVED col layout: Gxi[row][jg*16 + g*4 + jj] where the
// natural col is n = g*1024 + jg*4 + jj — so step-kernel block jg reads one
// contiguous 64B line per 4 output rows. grid 66*256 blocks x 256 thr;
// block = 32 rows x 16 interleaved cols; 4 waves split K (4 x 128).
// Same verified MFMA fragment pattern / 3-term hi-lo math as the step kernel.
// ---------------------------------------------------------------------------
template<bool PRESPLIT>
__global__ __launch_bounds__(256) void gx_gemm(
    const unsigned short* __restrict__ Xhi,    // [2112, 512]
    const unsigned short* __restrict__ Xlo,
    const unsigned short* __restrict__ Wihhi,  // [4096, 512] bf16 hi
    const unsigned short* __restrict__ Wihlo,
    const float* __restrict__ w_ih,            // fallback fp32
    const float* __restrict__ bsum,            // [4096]
    float* __restrict__ Gxi)                   // [2112, 4096] interleaved
{
    int bx   = blockIdx.x;
    int jg   = bx & 255;
    int m0   = (bx >> 8) * 32;    // 0..65 -> rows m0..m0+31
    int wave = threadIdx.x >> 6;  // 0..3 : K-chunk of 128
    int lane = threadIdx.x & 63;
    int lm   = lane & 15;
    int kq   = (lane >> 4) * 8;
    int tid  = threadIdx.x;
    int nrow = (lm >> 2) * H_ + jg * 4 + (lm & 3);
    int k0   = wave * 128;

    const unsigned short* Bhi = nullptr;
    const unsigned short* Blo = nullptr;
    const float* Bf = nullptr;
    if (PRESPLIT) { Bhi = Wihhi + (size_t)nrow * E_; Blo = Wihlo + (size_t)nrow * E_; }
    else          { Bf  = w_ih + (size_t)nrow * E_; }

    f32x4 acc0 = f32x4{0.f, 0.f, 0.f, 0.f};
    f32x4 acc1 = f32x4{0.f, 0.f, 0.f, 0.f};

#pragma unroll
    for (int kk = 0; kk < 128; kk += 32) {
        int k = k0 + kk + kq;
        bf16x8 bhi, blo;
        if constexpr (PRESPLIT) {
            bhi = *reinterpret_cast<const bf16x8*>(Bhi + k);
            blo = *reinterpret_cast<const bf16x8*>(Blo + k);
        } else {
            load_f32x8_hilo(Bf + k, bhi, blo);
        }
        bf16x8 a0h = *reinterpret_cast<const bf16x8*>(Xhi + (size_t)(m0 + lm) * E_ + k);
        bf16x8 a0l = *reinterpret_cast<const bf16x8*>(Xlo + (size_t)(m0 + lm) * E_ + k);
        bf16x8 a1h = *reinterpret_cast<const bf16x8*>(Xhi + (size_t)(m0 + 16 + lm) * E_ + k);
        bf16x8 a1l = *reinterpret_cast<const bf16x8*>(Xlo + (size_t)(m0 + 16 + lm) * E_ + k);
        acc0 = __builtin_amdgcn_mfma_f32_16x16x32_bf16(a0h, bhi, acc0, 0, 0, 0);
        acc0 = __builtin_amdgcn_mfma_f32_16x16x32_bf16(a0l, bhi, acc0, 0, 0, 0);
        acc0 = __builtin_amdgcn_mfma_f32_16x16x32_bf16(a0h, blo, acc0, 0, 0, 0);
        acc1 = __builtin_amdgcn_mfma_f32_16x16x32_bf16(a1h, bhi, acc1, 0, 0, 0);
        acc1 = __builtin_amdgcn_mfma_f32_16x16x32_bf16(a1l, bhi, acc1, 0, 0, 0);
        acc1 = __builtin_amdgcn_mfma_f32_16x16x32_bf16(a1h, blo, acc1, 0, 0, 0);
    }

    __shared__ float pbuf[4][2][16][17];
    int rbase = (lane >> 4) * 4;   // C/D: col=lane&15, row=(lane>>4)*4+r (verified)
#pragma unroll
    for (int r = 0; r < 4; ++r) {
        pbuf[wave][0][rbase + r][lm] = acc0[r];
        pbuf[wave][1][rbase + r][lm] = acc1[r];
    }
    __syncthreads();

    // reduce 4 K-partials + bias; write interleaved Gxi
    for (int idx = tid; idx < 512; idx += 256) {
        int mt = idx >> 8, rc = idx & 255;
        int row = rc >> 4, col = rc & 15;
        float v = pbuf[0][mt][row][col] + pbuf[1][mt][row][col]
                + pbuf[2][mt][row][col] + pbuf[3][mt][row][col];
        int n = (col >> 2) * H_ + jg * 4 + (col & 3);
        Gxi[(size_t)(m0 + mt * 16 + row) * NG_ + jg * 16 + col] = v + bsum[n];
    }
}

// ---------------------------------------------------------------------------
// Kernel 3a (persistent, cooperative): ALL 33 LSTM steps, h-GEMM ONLY.
// r6 structure (verified: write-once hseq, sc h-stores, flag/checker barrier)
// with the x-part hoisted into gx_gemm: per step each block computes
// h @ w_hh^T for its 16 gate-interleaved rows (4 waves x K=256), adds the
// precomputed Gxi tile, pointwise, h exchange. Block 384->256 threads.
// ---------------------------------------------------------------------------
template<bool PRESPLIT>
__global__ __launch_bounds__(256, 2) void lstm_persist(
    const float* __restrict__ Gxi,             // [2112, 4096] interleaved
    const unsigned short* __restrict__ Whhhi,  // [4096, 1024] bf16 hi
    const unsigned short* __restrict__ Whhlo,
    const float* __restrict__ w_hh,            // fallback fp32
    unsigned int* __restrict__ hseq,           // [34][64*1024] write-once
    float* __restrict__ c,                     // [64, 1024] (block-local)
    float* __restrict__ out,                   // [B][S][H] fp32
    unsigned int* __restrict__ flags,          // [512 * 32]
    unsigned int* __restrict__ gen)            // gen[0], gen[64]
{
    int bx   = blockIdx.x;
    int jg   = bx & 255;          // 4-col group within H
    int mgrp = bx >> 8;           // 0..1 : 32-batch group
    int wave = threadIdx.x >> 6;  // 0..3 : K-chunk of 256
    int lane = threadIdx.x & 63;
    int lm   = lane & 15;
    int kq   = (lane >> 4) * 8;
    int tid  = threadIdx.x;

    int gbase    = bx & 256;           // first block of my group (0 or 256)
    bool checker = (bx == gbase);
    unsigned int* mygen = gen + (mgrp * 64);

    int nrow = (lm >> 2) * H_ + jg * 4 + (lm & 3);
    int k0   = wave * 256;

    const unsigned short* Bhi = nullptr;
    const unsigned short* Blo = nullptr;
    const float* Bf = nullptr;
    if (PRESPLIT) { Bhi = Whhhi + (size_t)nrow * H_; Blo = Whhlo + (size_t)nrow * H_; }
    else          { Bf  = w_hh + (size_t)nrow * H_; }

    __shared__ float pbuf[4][2][16][17];
    __shared__ float gbuf[2][16][17];
    int rbase = (lane >> 4) * 4;

    for (int t = 0; t < S_; ++t) {
        const unsigned int* hpk_in = hseq + (size_t)t * HB_;
        unsigned int*      hpk_out = hseq + (size_t)(t + 1) * HB_;
        const unsigned int* hrow0 = hpk_in + (size_t)(mgrp * 32 + lm) * H_;
        const unsigned int* hrow1 = hpk_in + (size_t)(mgrp * 32 + 16 + lm) * H_;

        f32x4 acc0 = f32x4{0.f, 0.f, 0.f, 0.f};
        f32x4 acc1 = f32x4{0.f, 0.f, 0.f, 0.f};

#pragma unroll
        for (int kk = 0; kk < 256; kk += 32) {
            int k = k0 + kk + kq;
            bf16x8 bhi, blo;
            if constexpr (PRESPLIT) {
                bhi = *reinterpret_cast<const bf16x8*>(Bhi + k);
                blo = *reinterpret_cast<const bf16x8*>(Blo + k);
            } else {
                load_f32x8_hilo(Bf + k, bhi, blo);
            }
            bf16x8 a0h, a0l, a1h, a1l;
            load_hpk8(hrow0 + k, a0h, a0l);
            load_hpk8(hrow1 + k, a1h, a1l);
            acc0 = __builtin_amdgcn_mfma_f32_16x16x32_bf16(a0h, bhi, acc0, 0, 0, 0);
            acc0 = __builtin_amdgcn_mfma_f32_16x16x32_bf16(a0l, bhi, acc0, 0, 0, 0);
            acc0 = __builtin_amdgcn_mfma_f32_16x16x32_bf16(a0h, blo, acc0, 0, 0, 0);
            acc1 = __builtin_amdgcn_mfma_f32_16x16x32_bf16(a1h, bhi, acc1, 0, 0, 0);
            acc1 = __builtin_amdgcn_mfma_f32_16x16x32_bf16(a1l, bhi, acc1, 0, 0, 0);
            acc1 = __builtin_amdgcn_mfma_f32_16x16x32_bf16(a1h, blo, acc1, 0, 0, 0);
        }

#pragma unroll
        for (int r = 0; r < 4; ++r) {
            pbuf[wave][0][rbase + r][lm] = acc0[r];
            pbuf[wave][1][rbase + r][lm] = acc1[r];
        }
        __syncthreads();

        // reduce 4 K-partials: 512 values over 256 threads
        for (int idx = tid; idx < 512; idx += 256) {
            int mt = idx >> 8, rc = idx & 255;
            int row = rc >> 4, col = rc & 15;
            gbuf[mt][row][col] = pbuf[0][mt][row][col] + pbuf[1][mt][row][col]
                               + pbuf[2][mt][row][col] + pbuf[3][mt][row][col];
        }
        __syncthreads();

        // fused pointwise: gates = Gxi + h-GEMM; 128 outputs
        if (tid < 128) {
            int mt = tid >> 6, bl = (tid >> 2) & 15, jj = tid & 3;
            int b = mgrp * 32 + mt * 16 + bl;
            int j = jg * 4 + jj;
            const float* gx = Gxi + (size_t)(t * 64 + b) * NG_ + jg * 16;
            float iv = gbuf[mt][bl][ 0 + jj] + gx[ 0 + jj];
            float fv = gbuf[mt][bl][ 4 + jj] + gx[ 4 + jj];
            float gv = gbuf[mt][bl][ 8 + jj] + gx[ 8 + jj];
            float ov = gbuf[mt][bl][12 + jj] + gx[12 + jj];
            float si = 1.f / (1.f + expf(-iv));
            float sf = 1.f / (1.f + expf(-fv));
            float so = 1.f / (1.f + expf(-ov));
            float tg = tanhf(gv);
            size_t cidx = (size_t)b * H_ + j;
            float cn = sf * c[cidx] + si * tg;
            c[cidx] = cn;
            float hn = so * tanhf(cn);
            unsigned short hi, lo; split2(hn, hi, lo);
            __hip_atomic_store(&hpk_out[cidx],
                               (unsigned int)hi | ((unsigned int)lo << 16),
                               __ATOMIC_RELAXED, __HIP_MEMORY_SCOPE_AGENT);
            out[((size_t)b * S_ + t) * H_ + j] = hn;
        }

        // ---- flag/checker barrier, per batch-half group (r6-verified) ----
        __syncthreads();   // drains vmcnt(0) on every wave -> h stores visible
        unsigned int target = (unsigned int)(t + 1);
        if (!checker) {
            if (tid == 0) {
                __hip_atomic_store(&flags[(size_t)bx * 32], target,
                                   __ATOMIC_RELAXED, __HIP_MEMORY_SCOPE_AGENT);
                while (__hip_atomic_load(mygen, __ATOMIC_RELAXED,
                                         __HIP_MEMORY_SCOPE_AGENT) < target) {
                    __builtin_amdgcn_s_sleep(2);
                }
            }
        } else {
            int fi = gbase + 1 + tid;          // valid for tid < 255
            bool need = (tid < 255);
            for (;;) {
                int ok = 1;
                if (need) {
                    ok = (__hip_atomic_load(&flags[(size_t)fi * 32],
                                            __ATOMIC_RELAXED,
                                            __HIP_MEMORY_SCOPE_AGENT) >= target);
                }
                if (__syncthreads_and(ok)) break;
                __builtin_amdgcn_s_sleep(2);
            }
            if (tid == 0) {
                __hip_atomic_store(mygen, target,
                                   __ATOMIC_RELAXED, __HIP_MEMORY_SCOPE_AGENT);
            }
        }
        __syncthreads();
    }
}

// ---------------------------------------------------------------------------
// Kernel 3b: single-step fallback if cooperative launch is unavailable.
// ---------------------------------------------------------------------------
template<bool PRESPLIT>
__global__ __launch_bounds__(256) void lstm_step(
    const float* __restrict__ Gxi,
    const unsigned short* __restrict__ Whhhi,
    const unsigned short* __restrict__ Whhlo,
    const float* __restrict__ w_hh,
    const unsigned int* __restrict__ hpk_in,
    float* __restrict__ c,
    unsigned int* __restrict__ hpk_out,
    float* __restrict__ out,
    int t)
{
    int bx   = blockIdx.x;
    int jg   = bx & 255;
    int mgrp = bx >> 8;
    int wave = threadIdx.x >> 6;
    int lane = threadIdx.x & 63;
    int lm   = lane & 15;
    int kq   = (lane >> 4) * 8;
    int tid  = threadIdx.x;
    int nrow = (lm >> 2) * H_ + jg * 4 + (lm & 3);
    int k0   = wave * 256;

    const unsigned short* Bhi = nullptr;
    const unsigned short* Blo = nullptr;
    const float* Bf = nullptr;
    if (PRESPLIT) { Bhi = Whhhi + (size_t)nrow * H_; Blo = Whhlo + (size_t)nrow * H_; }
    else          { Bf  = w_hh + (size_t)nrow * H_; }

    const unsigned int* hrow0 = hpk_in + (size_t)(mgrp * 32 + lm) * H_;
    const unsigned int* hrow1 = hpk_in + (size_t)(mgrp * 32 + 16 + lm) * H_;

    f32x4 acc0 = f32x4{0.f, 0.f, 0.f, 0.f};
    f32x4 acc1 = f32x4{0.f, 0.f, 0.f, 0.f};

#pragma unroll
    for (int kk = 0; kk < 256; kk += 32) {
        int k = k0 + kk + kq;
        bf16x8 bhi, blo;
        if constexpr (PRESPLIT) {
            bhi = *reinterpret_cast<const bf16x8*>(Bhi + k);
            blo = *reinterpret_cast<const bf16x8*>(Blo + k);
        } else {
            load_f32x8_hilo(Bf + k, bhi, blo);
        }
        bf16x8 a0h, a0l, a1h, a1l;
        load_hpk8(hrow0 + k, a0h, a0l);
        load_hpk8(hrow1 + k, a1h, a1l);
        acc0 = __builtin_amdgcn_mfma_f32_16x16x32_bf16(a0h, bhi, acc0, 0, 0, 0);
        acc0 = __builtin_amdgcn_mfma_f32_16x16x32_bf16(a0l, bhi, acc0, 0, 0, 0);
        acc0 = __builtin_amdgcn_mfma_f32_16x16x32_bf16(a0h, blo, acc0, 0, 0, 0);
        acc1 = __builtin_amdgcn_mfma_f32_16x16x32_bf16(a1h, bhi, acc1, 0, 0, 0);
        acc1 = __builtin_amdgcn_mfma_f32_16x16x32_bf16(a1l, bhi, acc1, 0, 0, 0);
        acc1 = __builtin_amdgcn_mfma_f32_16x16x32_bf16(a1h, blo, acc1, 0, 0, 0);
    }

    __shared__ float pbuf[4][2][16][17];
    __shared__ float gbuf[2][16][17];
    int rbase = (lane >> 4) * 4;
#pragma unroll
    for (int r = 0; r < 4; ++r) {
        pbuf[wave][0][rbase + r][lm] = acc0[r];
        pbuf[wave][1][rbase + r][lm] = acc1[r];
    }
    __syncthreads();

    for (int idx = tid; idx < 512; idx += 256) {
        int mt = idx >> 8, rc = idx & 255;
        int row = rc >> 4, col = rc & 15;
        gbuf[mt][row][col] = pbuf[0][mt][row][col] + pbuf[1][mt][row][col]
                           + pbuf[2][mt][row][col] + pbuf[3][mt][row][col];
    }
    __syncthreads();

    if (tid < 128) {
        int mt = tid >> 6, bl = (tid >> 2) & 15, jj = tid & 3;
        int b = mgrp * 32 + mt * 16 + bl;
        int j = jg * 4 + jj;
        const float* gx = Gxi + (size_t)(t * 64 + b) * NG_ + jg * 16;
        float iv = gbuf[mt][bl][ 0 + jj] + gx[ 0 + jj];
        float fv = gbuf[mt][bl][ 4 + jj] + gx[ 4 + jj];
        float gv = gbuf[mt][bl][ 8 + jj] + gx[ 8 + jj];
        float ov = gbuf[mt][bl][12 + jj] + gx[12 + jj];
        float si = 1.f / (1.f + expf(-iv));
        float sf = 1.f / (1.f + expf(-fv));
        float so = 1.f / (1.f + expf(-ov));
        float tg = tanhf(gv);
        size_t cidx = (size_t)b * H_ + j;
        float cn = sf * c[cidx] + si * tg;
        c[cidx] = cn;
        float hn = so * tanhf(cn);
        unsigned short hi, lo; split2(hn, hi, lo);
        hpk_out[cidx] = (unsigned int)hi | ((unsigned int)lo << 16);
        out[((size_t)b * S_ + t) * H_ + j] = hn;
    }
}

// ---------------------------------------------------------------------------
extern "C" void kernel_launch(void* const* d_in, const int* in_sizes, int n_in,
                              void* d_out, int out_size, void* d_ws, size_t ws_size,
                              hipStream_t stream)
{
    // Positional defaults (setup_inputs dict order)...
    const float* feat = (const float*)d_in[0];
    const int*   caps = (const int*)d_in[1];
    const float* Wemb = (const float*)d_in[2];
    const float* bemb = (const float*)d_in[3];
    const float* w_ih = (const float*)d_in[4];
    const float* w_hh = (const float*)d_in[5];
    const float* b_ih = (const float*)d_in[6];
    const float* b_hh = (const float*)d_in[7];
    const float* h0   = (const float*)d_in[8];
    const float* c0   = (const float*)d_in[9];
    int nbias = 0, nstate = 0;
    for (int i = 0; i < n_in; ++i) {
        switch (in_sizes[i]) {
            case 64 * 512:        feat = (const float*)d_in[i]; break;
            case 64 * 32:         caps = (const int*)d_in[i];   break;
            case 512 * 32000:     Wemb = (const float*)d_in[i]; break;
            case 512:             bemb = (const float*)d_in[i]; break;
            case 4096 * 512:      w_ih = (const float*)d_in[i]; break;
            case 4096 * 1024:     w_hh = (const float*)d_in[i]; break;
            case 4096:
                if (nbias++ == 0) b_ih = (const float*)d_in[i];
                else              b_hh = (const float*)d_in[i];
                break;
            case 64 * 1024:
                if (nstate++ == 0) h0 = (const float*)d_in[i];
                else               c0 = (const float*)d_in[i];
                break;
            default: break;
        }
    }
    float* out = (float*)d_out;

    // workspace layout (~73 MB total; ws is 256 MB per fill-kernel evidence)
    char* ws = (char*)d_ws;
    unsigned short* Xhi  = (unsigned short*)ws; ws += (size_t)2112 * 512 * 2;
    unsigned short* Xlo  = (unsigned short*)ws; ws += (size_t)2112 * 512 * 2;
    float* Gxi           = (float*)ws;          ws += (size_t)2112 * NG_ * 4;   // 34.6MB
    unsigned int* hseq   = (unsigned int*)ws;   ws += (size_t)(S_ + 1) * HB_ * 4; // 8.9MB
    float* cbuf          = (float*)ws;          ws += (size_t)B_ * H_ * 4;
    float* bsum          = (float*)ws;          ws += (size_t)4096 * 4;
    unsigned int* flags  = (unsigned int*)ws;   ws += (size_t)512 * 32 * 4;
    unsigned int* gen    = (unsigned int*)ws;   ws += (size_t)128 * 4;
    unsigned short* Wihhi = (unsigned short*)ws; ws += (size_t)4096 * 512 * 2;
    unsigned short* Wihlo = (unsigned short*)ws; ws += (size_t)4096 * 512 * 2;
    unsigned short* Whhhi = (unsigned short*)ws; ws += (size_t)4096 * 1024 * 2;
    unsigned short* Whhlo = (unsigned short*)ws; ws += (size_t)4096 * 1024 * 2;
    size_t needed = (size_t)(ws - (char*)d_ws);
    bool presplit = ws_size >= needed;

    build_x<<<2112, 512, 0, stream>>>(feat, caps, Wemb, bemb, Xhi, Xlo);
    init_state<<<256, 256, 0, stream>>>(h0, c0, hseq, cbuf, flags, gen);
    bias_sum<<<16, 256, 0, stream>>>(b_ih, b_hh, bsum);
    if (presplit) {
        split_w<<<2048, 256, 0, stream>>>(w_ih, Wihhi, Wihlo, (4096 * 512) / 4);
        split_w<<<2048, 256, 0, stream>>>(w_hh, Whhhi, Whhlo, (4096 * 1024) / 4);
        gx_gemm<true><<<66 * 256, 256, 0, stream>>>(Xhi, Xlo, Wihhi, Wihlo,
                                                    w_ih, bsum, Gxi);
    } else {
        gx_gemm<false><<<66 * 256, 256, 0, stream>>>(Xhi, Xlo, Wihhi, Wihlo,
                                                     w_ih, bsum, Gxi);
    }

    // --- persistent cooperative path ---
    void* args[] = {
        (void*)&Gxi,
        (void*)&Whhhi, (void*)&Whhlo, (void*)&w_hh,
        (void*)&hseq, (void*)&cbuf, (void*)&out,
        (void*)&flags, (void*)&gen
    };
    const void* pk = presplit ? (const void*)lstm_persist<true>
                              : (const void*)lstm_persist<false>;
    hipError_t err = hipLaunchCooperativeKernel(pk, dim3(512), dim3(256),
                                                args, 0, stream);
    if (err != hipSuccess) {
        (void)hipGetLastError();   // clear sticky error, fall back
        for (int t = 0; t < S_; ++t) {
            const unsigned int* hin = hseq + (size_t)t * HB_;
            unsigned int*      hout = hseq + (size_t)(t + 1) * HB_;
            if (presplit) {
                lstm_step<true><<<512, 256, 0, stream>>>(
                    Gxi, Whhhi, Whhlo, w_hh, hin, cbuf, hout, out, t);
            } else {
                lstm_step<false><<<512, 256, 0, stream>>>(
                    Gxi, Whhhi, Whhlo, w_hh, hin, cbuf, hout, out, t);
            }
        }
    }
}

// Round 8
// 695.732 us; speedup vs baseline: 5.2644x; 1.0353x over previous
//
#include <hip/hip_runtime.h>
#include <hip/hip_bf16.h>

// Problem constants
#define B_   64
#define T_   32
#define S_   33      // T+1 LSTM steps
#define V_   32000
#define E_   512
#define H_   1024
#define HB_  (B_ * H_)   // one h buffer, in uints (packed hi|lo)
#define NG_  4096        // 4 gates * H

typedef __attribute__((ext_vector_type(8))) short  bf16x8;
typedef __attribute__((ext_vector_type(4))) float  f32x4;

// Split fp32 into hi/lo bf16 pair: x ~= hi + lo  (error ~2^-16 rel)
__device__ inline void split2(float x, unsigned short& hi, unsigned short& lo) {
    __hip_bfloat16 h = __float2bfloat16(x);
    float r = x - __bfloat162float(h);
    __hip_bfloat16 l = __float2bfloat16(r);
    hi = *reinterpret_cast<unsigned short*>(&h);
    lo = *reinterpret_cast<unsigned short*>(&l);
}

// Load 8 contiguous fp32 and split into hi/lo bf16x8 fragments (fallback path).
__device__ inline void load_f32x8_hilo(const float* __restrict__ p,
                                       bf16x8& hi, bf16x8& lo) {
    const float4* q = reinterpret_cast<const float4*>(p);
    float4 v0 = q[0], v1 = q[1];
    float f[8] = {v0.x, v0.y, v0.z, v0.w, v1.x, v1.y, v1.z, v1.w};
#pragma unroll
    for (int j = 0; j < 8; ++j) {
        unsigned short h, l; split2(f[j], h, l);
        hi[j] = (short)h; lo[j] = (short)l;
    }
}

// Load 8 packed-h uints (hi | lo<<16) with NORMAL cached loads and unpack.
// Safe: hseq buffers are write-once (r6-verified).
__device__ inline void load_hpk8(const unsigned int* __restrict__ p,
                                 bf16x8& hi, bf16x8& lo) {
    uint4 v0 = *reinterpret_cast<const uint4*>(p);
    uint4 v1 = *reinterpret_cast<const uint4*>(p + 4);
    unsigned int w[8] = {v0.x, v0.y, v0.z, v0.w, v1.x, v1.y, v1.z, v1.w};
#pragma unroll
    for (int j = 0; j < 8; ++j) {
        hi[j] = (short)(w[j] & 0xffffu);
        lo[j] = (short)(w[j] >> 16);
    }
}

// ---------------------------------------------------------------------------
// Kernel 1: build X[t*64+b, e]  (time-major) as hi/lo bf16.
// ---------------------------------------------------------------------------
__global__ __launch_bounds__(512) void build_x(
    const float* __restrict__ feat,   // [B,E]
    const int*   __restrict__ caps,   // [B,T] int32
    const float* __restrict__ Wemb,   // [E,V]
    const float* __restrict__ bemb,   // [E]
    unsigned short* __restrict__ Xhi,
    unsigned short* __restrict__ Xlo)
{
    int row = blockIdx.x;          // t*64 + b
    int t = row >> 6, b = row & 63;
    int e = threadIdx.x;
    float x;
    if (t == 0) {
        x = feat[b * E_ + e];
    } else {
        int cap = caps[b * T_ + (t - 1)];
        x = Wemb[(size_t)e * V_ + cap] + bemb[e];
    }
    unsigned short hi, lo; split2(x, hi, lo);
    Xhi[(size_t)row * E_ + e] = hi;
    Xlo[(size_t)row * E_ + e] = lo;
}

// ---------------------------------------------------------------------------
// Kernel 2: init LSTM state.  h -> packed uint (hi | lo<<16) into hseq[0],
// c fp32.  Also zeroes barrier flags + distributed gen copies.
// ---------------------------------------------------------------------------
__global__ __launch_bounds__(256) void init_state(
    const float* __restrict__ h0,
    const float* __restrict__ c0,
    unsigned int* __restrict__ hseq0,
    float* __restrict__ c,
    unsigned int* __restrict__ flags,   // [512 * 32] (128B-padded per block)
    unsigned int* __restrict__ gen)     // [2*64*32] (64 copies per group)
{
    int idx = blockIdx.x * 256 + threadIdx.x;
    if (idx < 512 * 32)  flags[idx] = 0u;
    if (idx < 2 * 64 * 32) gen[idx] = 0u;
    unsigned short hi, lo; split2(h0[idx], hi, lo);
    hseq0[idx] = (unsigned int)hi | ((unsigned int)lo << 16);
    c[idx]   = c0[idx];
}

// ---------------------------------------------------------------------------
// Kernel 2b: pre-split fp32 weights into bf16 hi/lo (once).
// ---------------------------------------------------------------------------
__global__ __launch_bounds__(256) void split_w(
    const float* __restrict__ src,
    unsigned short* __restrict__ hi,
    unsigned short* __restrict__ lo,
    int n4)
{
    int idx = blockIdx.x * 256 + threadIdx.x;
    int stride = gridDim.x * 256;
    for (; idx < n4; idx += stride) {
        float4 v = reinterpret_cast<const float4*>(src)[idx];
        float f[4] = {v.x, v.y, v.z, v.w};
        unsigned short h[4], l[4];
#pragma unroll
        for (int j = 0; j < 4; ++j) split2(f[j], h[j], l[j]);
        ushort4 hv; hv.x = h[0]; hv.y = h[1]; hv.z = h[2]; hv.w = h[3];
        ushort4 lv; lv.x = l[0]; lv.y = l[1]; lv.z = l[2]; lv.w = l[3];
        *reinterpret_cast<ushort4*>(hi + (size_t)idx * 4) = hv;
        *reinterpret_cast<ushort4*>(lo + (size_t)idx * 4) = lv;
    }
}

// Kernel 2c: bsum = b_ih + b_hh  (4096 elems)
__global__ __launch_bounds__(256) void bias_sum(
    const float* __restrict__ a, const float* __restrict__ b,
    float* __restrict__ s)
{
    int i = blockIdx.x * 256 + threadIdx.x;
    s[i] = a[i] + b[i];
}

// ---------------------------------------------------------------------------
// Kernel 2d: Gxi = X @ w_ih^T + bsum (r7-verified, unchanged).
// Gate-interleaved output: Gxi[row][jg*16 + g*4 + jj], n = g*1024 + jg*4 + jj.
// ---------------------------------------------------------------------------
template<bool PRESPLIT>
__global__ __launch_bounds__(256) void gx_gemm(
    const unsigned short* __restrict__ Xhi,    // [2112, 512]
    const unsigned short* __restrict__ Xlo,
    const unsigned short* __restrict__ Wihhi,  // [4096, 512] bf16 hi
    const unsigned short* __restrict__ Wihlo,
    const float* __restrict__ w_ih,            // fallback fp32
    const float* __restrict__ bsum,            // [4096]
    float* __restrict__ Gxi)                   // [2112, 4096] interleaved
{
    int bx   = blockIdx.x;
    int jg   = bx & 255;
    int m0   = (bx >> 8) * 32;
    int wave = threadIdx.x >> 6;
    int lane = threadIdx.x & 63;
    int lm   = lane & 15;
    int kq   = (lane >> 4) * 8;
    int tid  = threadIdx.x;
    int nrow = (lm >> 2) * H_ + jg * 4 + (lm & 3);
    int k0   = wave * 128;

    const unsigned short* Bhi = nullptr;
    const unsigned short* Blo = nullptr;
    const float* Bf = nullptr;
    if (PRESPLIT) { Bhi = Wihhi + (size_t)nrow * E_; Blo = Wihlo + (size_t)nrow * E_; }
    else          { Bf  = w_ih + (size_t)nrow * E_; }

    f32x4 acc0 = f32x4{0.f, 0.f, 0.f, 0.f};
    f32x4 acc1 = f32x4{0.f, 0.f, 0.f, 0.f};

#pragma unroll
    for (int kk = 0; kk < 128; kk += 32) {
        int k = k0 + kk + kq;
        bf16x8 bhi, blo;
        if constexpr (PRESPLIT) {
            bhi = *reinterpret_cast<const bf16x8*>(Bhi + k);
            blo = *reinterpret_cast<const bf16x8*>(Blo + k);
        } else {
            load_f32x8_hilo(Bf + k, bhi, blo);
        }
        bf16x8 a0h = *reinterpret_cast<const bf16x8*>(Xhi + (size_t)(m0 + lm) * E_ + k);
        bf16x8 a0l = *reinterpret_cast<const bf16x8*>(Xlo + (size_t)(m0 + lm) * E_ + k);
        bf16x8 a1h = *reinterpret_cast<const bf16x8*>(Xhi + (size_t)(m0 + 16 + lm) * E_ + k);
        bf16x8 a1l = *reinterpret_cast<const bf16x8*>(Xlo + (size_t)(m0 + 16 + lm) * E_ + k);
        acc0 = __builtin_amdgcn_mfma_f32_16x16x32_bf16(a0h, bhi, acc0, 0, 0, 0);
        acc0 = __builtin_amdgcn_mfma_f32_16x16x32_bf16(a0l, bhi, acc0, 0, 0, 0);
        acc0 = __builtin_amdgcn_mfma_f32_16x16x32_bf16(a0h, blo, acc0, 0, 0, 0);
        acc1 = __builtin_amdgcn_mfma_f32_16x16x32_bf16(a1h, bhi, acc1, 0, 0, 0);
        acc1 = __builtin_amdgcn_mfma_f32_16x16x32_bf16(a1l, bhi, acc1, 0, 0, 0);
        acc1 = __builtin_amdgcn_mfma_f32_16x16x32_bf16(a1h, blo, acc1, 0, 0, 0);
    }

    __shared__ float pbuf[4][2][16][17];
    int rbase = (lane >> 4) * 4;   // C/D: col=lane&15, row=(lane>>4)*4+r (verified)
#pragma unroll
    for (int r = 0; r < 4; ++r) {
        pbuf[wave][0][rbase + r][lm] = acc0[r];
        pbuf[wave][1][rbase + r][lm] = acc1[r];
    }
    __syncthreads();

    for (int idx = tid; idx < 512; idx += 256) {
        int mt = idx >> 8, rc = idx & 255;
        int row = rc >> 4, col = rc & 15;
        float v = pbuf[0][mt][row][col] + pbuf[1][mt][row][col]
                + pbuf[2][mt][row][col] + pbuf[3][mt][row][col];
        int n = (col >> 2) * H_ + jg * 4 + (col & 3);
        Gxi[(size_t)(m0 + mt * 16 + row) * NG_ + jg * 16 + col] = v + bsum[n];
    }
}

// ---------------------------------------------------------------------------
// Kernel 3a (persistent, cooperative): ALL 33 LSTM steps, h-GEMM only.
// r7 structure (verified) + 3 changes per r7 post-mortem:
//  (1) w_hh fragments preloaded into REGISTERS before the t-loop (8x hi/lo
//      bf16x8 = 64 VGPR/wave; weights time-invariant; occupancy grid-limited
//      so VGPRs free) -> K-loop is h-loads + MFMA only.
//  (2) Gxi tile prefetched at top of each step (h-independent) -> its
//      IC/L3 latency hides under the K-loop.
//  (3) gen broadcast distributed over 64 padded lines per group (4 spinner
//      blocks per line instead of 511 on one).
// Barrier/visibility pattern otherwise identical to r6/r7 (verified).
// ---------------------------------------------------------------------------
template<bool PRESPLIT>
__global__ __launch_bounds__(256, 2) void lstm_persist(
    const float* __restrict__ Gxi,             // [2112, 4096] interleaved
    const unsigned short* __restrict__ Whhhi,  // [4096, 1024] bf16 hi
    const unsigned short* __restrict__ Whhlo,
    const float* __restrict__ w_hh,            // fallback fp32
    unsigned int* __restrict__ hseq,           // [34][64*1024] write-once
    float* __restrict__ c,                     // [64, 1024] (block-local)
    float* __restrict__ out,                   // [B][S][H] fp32
    unsigned int* __restrict__ flags,          // [512 * 32]
    unsigned int* __restrict__ gen)            // [2][64][32] copies
{
    int bx   = blockIdx.x;
    int jg   = bx & 255;          // 4-col group within H
    int mgrp = bx >> 8;           // 0..1 : 32-batch group
    int wave = threadIdx.x >> 6;  // 0..3 : K-chunk of 256
    int lane = threadIdx.x & 63;
    int lm   = lane & 15;
    int kq   = (lane >> 4) * 8;
    int tid  = threadIdx.x;

    int gbase    = bx & 256;           // first block of my group (0 or 256)
    bool checker = (bx == gbase);
    // my gen copy: 4 spinner blocks per 128B line
    unsigned int* mygen = gen + ((size_t)mgrp * 64 + ((bx & 255) >> 2)) * 32;

    int nrow = (lm >> 2) * H_ + jg * 4 + (lm & 3);
    int k0   = wave * 256;

    // ---- (1) preload w_hh fragments into registers (time-invariant) ----
    bf16x8 wh[8], wl[8];
    if constexpr (PRESPLIT) {
        const unsigned short* Bhi = Whhhi + (size_t)nrow * H_ + k0 + kq;
        const unsigned short* Blo = Whhlo + (size_t)nrow * H_ + k0 + kq;
#pragma unroll
        for (int i = 0; i < 8; ++i) {
            wh[i] = *reinterpret_cast<const bf16x8*>(Bhi + i * 32);
            wl[i] = *reinterpret_cast<const bf16x8*>(Blo + i * 32);
        }
    } else {
        const float* Bf = w_hh + (size_t)nrow * H_ + k0 + kq;
#pragma unroll
        for (int i = 0; i < 8; ++i) {
            load_f32x8_hilo(Bf + i * 32, wh[i], wl[i]);
        }
    }

    __shared__ float pbuf[4][2][16][17];
    __shared__ float gbuf[2][16][17];
    int rbase = (lane >> 4) * 4;

    for (int t = 0; t < S_; ++t) {
        const unsigned int* hpk_in = hseq + (size_t)t * HB_;
        unsigned int*      hpk_out = hseq + (size_t)(t + 1) * HB_;
        const unsigned int* hrow0 = hpk_in + (size_t)(mgrp * 32 + lm) * H_ + k0 + kq;
        const unsigned int* hrow1 = hpk_in + (size_t)(mgrp * 32 + 16 + lm) * H_ + k0 + kq;

        // ---- (2) prefetch Gxi tile for this step (h-independent) ----
        float gx_i = 0.f, gx_f = 0.f, gx_g = 0.f, gx_o = 0.f;
        if (tid < 128) {
            int mt = tid >> 6, bl = (tid >> 2) & 15, jj = tid & 3;
            int b = mgrp * 32 + mt * 16 + bl;
            const float* gx = Gxi + (size_t)(t * 64 + b) * NG_ + jg * 16;
            gx_i = gx[ 0 + jj];
            gx_f = gx[ 4 + jj];
            gx_g = gx[ 8 + jj];
            gx_o = gx[12 + jj];
        }

        f32x4 acc0 = f32x4{0.f, 0.f, 0.f, 0.f};
        f32x4 acc1 = f32x4{0.f, 0.f, 0.f, 0.f};

#pragma unroll
        for (int i = 0; i < 8; ++i) {
            bf16x8 a0h, a0l, a1h, a1l;
            load_hpk8(hrow0 + i * 32, a0h, a0l);
            load_hpk8(hrow1 + i * 32, a1h, a1l);
            acc0 = __builtin_amdgcn_mfma_f32_16x16x32_bf16(a0h, wh[i], acc0, 0, 0, 0);
            acc0 = __builtin_amdgcn_mfma_f32_16x16x32_bf16(a0l, wh[i], acc0, 0, 0, 0);
            acc0 = __builtin_amdgcn_mfma_f32_16x16x32_bf16(a0h, wl[i], acc0, 0, 0, 0);
            acc1 = __builtin_amdgcn_mfma_f32_16x16x32_bf16(a1h, wh[i], acc1, 0, 0, 0);
            acc1 = __builtin_amdgcn_mfma_f32_16x16x32_bf16(a1l, wh[i], acc1, 0, 0, 0);
            acc1 = __builtin_amdgcn_mfma_f32_16x16x32_bf16(a1h, wl[i], acc1, 0, 0, 0);
        }

#pragma unroll
        for (int r = 0; r < 4; ++r) {
            pbuf[wave][0][rbase + r][lm] = acc0[r];
            pbuf[wave][1][rbase + r][lm] = acc1[r];
        }
        __syncthreads();

        // reduce 4 K-partials: 512 values over 256 threads
        for (int idx = tid; idx < 512; idx += 256) {
            int mt = idx >> 8, rc = idx & 255;
            int row = rc >> 4, col = rc & 15;
            gbuf[mt][row][col] = pbuf[0][mt][row][col] + pbuf[1][mt][row][col]
                               + pbuf[2][mt][row][col] + pbuf[3][mt][row][col];
        }
        __syncthreads();

        // fused pointwise: gates = prefetched Gxi + h-GEMM; 128 outputs
        if (tid < 128) {
            int mt = tid >> 6, bl = (tid >> 2) & 15, jj = tid & 3;
            int b = mgrp * 32 + mt * 16 + bl;
            int j = jg * 4 + jj;
            float iv = gbuf[mt][bl][ 0 + jj] + gx_i;
            float fv = gbuf[mt][bl][ 4 + jj] + gx_f;
            float gv = gbuf[mt][bl][ 8 + jj] + gx_g;
            float ov = gbuf[mt][bl][12 + jj] + gx_o;
            float si = 1.f / (1.f + expf(-iv));
            float sf = 1.f / (1.f + expf(-fv));
            float so = 1.f / (1.f + expf(-ov));
            float tg = tanhf(gv);
            size_t cidx = (size_t)b * H_ + j;
            float cn = sf * c[cidx] + si * tg;
            c[cidx] = cn;
            float hn = so * tanhf(cn);
            unsigned short hi, lo; split2(hn, hi, lo);
            __hip_atomic_store(&hpk_out[cidx],
                               (unsigned int)hi | ((unsigned int)lo << 16),
                               __ATOMIC_RELAXED, __HIP_MEMORY_SCOPE_AGENT);
            out[((size_t)b * S_ + t) * H_ + j] = hn;
        }

        // ---- flag/checker barrier with distributed gen (r6/r7 pattern) ----
        __syncthreads();   // drains vmcnt(0) on every wave -> h stores visible
        unsigned int target = (unsigned int)(t + 1);
        if (!checker) {
            if (tid == 0) {
                __hip_atomic_store(&flags[(size_t)bx * 32], target,
                                   __ATOMIC_RELAXED, __HIP_MEMORY_SCOPE_AGENT);
                while (__hip_atomic_load(mygen, __ATOMIC_RELAXED,
                                         __HIP_MEMORY_SCOPE_AGENT) < target) {
                    __builtin_amdgcn_s_sleep(2);
                }
            }
        } else {
            int fi = gbase + 1 + tid;          // valid for tid < 255
            bool need = (tid < 255);
            for (;;) {
                int ok = 1;
                if (need) {
                    ok = (__hip_atomic_load(&flags[(size_t)fi * 32],
                                            __ATOMIC_RELAXED,
                                            __HIP_MEMORY_SCOPE_AGENT) >= target);
                }
                if (__syncthreads_and(ok)) break;
                __builtin_amdgcn_s_sleep(2);
            }
            // (3) broadcast: 64 threads store 64 padded gen copies
            if (tid < 64) {
                __hip_atomic_store(gen + ((size_t)mgrp * 64 + tid) * 32, target,
                                   __ATOMIC_RELAXED, __HIP_MEMORY_SCOPE_AGENT);
            }
        }
        __syncthreads();   // all threads held until tid0's spin exit
    }
}

// ---------------------------------------------------------------------------
// Kernel 3b: single-step fallback if cooperative launch is unavailable
// (r7-verified; kernel boundaries provide visibility).
// ---------------------------------------------------------------------------
template<bool PRESPLIT>
__global__ __launch_bounds__(256) void lstm_step(
    const float* __restrict__ Gxi,
    const unsigned short* __restrict__ Whhhi,
    const unsigned short* __restrict__ Whhlo,
    const float* __restrict__ w_hh,
    const unsigned int* __restrict__ hpk_in,
    float* __restrict__ c,
    unsigned int* __restrict__ hpk_out,
    float* __restrict__ out,
    int t)
{
    int bx   = blockIdx.x;
    int jg   = bx & 255;
    int mgrp = bx >> 8;
    int wave = threadIdx.x >> 6;
    int lane = threadIdx.x & 63;
    int lm   = lane & 15;
    int kq   = (lane >> 4) * 8;
    int tid  = threadIdx.x;
    int nrow = (lm >> 2) * H_ + jg * 4 + (lm & 3);
    int k0   = wave * 256;

    const unsigned short* Bhi = nullptr;
    const unsigned short* Blo = nullptr;
    const float* Bf = nullptr;
    if (PRESPLIT) { Bhi = Whhhi + (size_t)nrow * H_; Blo = Whhlo + (size_t)nrow * H_; }
    else          { Bf  = w_hh + (size_t)nrow * H_; }

    const unsigned int* hrow0 = hpk_in + (size_t)(mgrp * 32 + lm) * H_;
    const unsigned int* hrow1 = hpk_in + (size_t)(mgrp * 32 + 16 + lm) * H_;

    f32x4 acc0 = f32x4{0.f, 0.f, 0.f, 0.f};
    f32x4 acc1 = f32x4{0.f, 0.f, 0.f, 0.f};

#pragma unroll
    for (int kk = 0; kk < 256; kk += 32) {
        int k = k0 + kk + kq;
        bf16x8 bhi, blo;
        if constexpr (PRESPLIT) {
            bhi = *reinterpret_cast<const bf16x8*>(Bhi + k);
            blo = *reinterpret_cast<const bf16x8*>(Blo + k);
        } else {
            load_f32x8_hilo(Bf + k, bhi, blo);
        }
        bf16x8 a0h, a0l, a1h, a1l;
        load_hpk8(hrow0 + k, a0h, a0l);
        load_hpk8(hrow1 + k, a1h, a1l);
        acc0 = __builtin_amdgcn_mfma_f32_16x16x32_bf16(a0h, bhi, acc0, 0, 0, 0);
        acc0 = __builtin_amdgcn_mfma_f32_16x16x32_bf16(a0l, bhi, acc0, 0, 0, 0);
        acc0 = __builtin_amdgcn_mfma_f32_16x16x32_bf16(a0h, blo, acc0, 0, 0, 0);
        acc1 = __builtin_amdgcn_mfma_f32_16x16x32_bf16(a1h, bhi, acc1, 0, 0, 0);
        acc1 = __builtin_amdgcn_mfma_f32_16x16x32_bf16(a1l, bhi, acc1, 0, 0, 0);
        acc1 = __builtin_amdgcn_mfma_f32_16x16x32_bf16(a1h, blo, acc1, 0, 0, 0);
    }

    __shared__ float pbuf[4][2][16][17];
    __shared__ float gbuf[2][16][17];
    int rbase = (lane >> 4) * 4;
#pragma unroll
    for (int r = 0; r < 4; ++r) {
        pbuf[wave][0][rbase + r][lm] = acc0[r];
        pbuf[wave][1][rbase + r][lm] = acc1[r];
    }
    __syncthreads();

    for (int idx = tid; idx < 512; idx += 256) {
        int mt = idx >> 8, rc = idx & 255;
        int row = rc >> 4, col = rc & 15;
        gbuf[mt][row][col] = pbuf[0][mt][row][col] + pbuf[1][mt][row][col]
                           + pbuf[2][mt][row][col] + pbuf[3][mt][row][col];
    }
    __syncthreads();

    if (tid < 128) {
        int mt = tid >> 6, bl = (tid >> 2) & 15, jj = tid & 3;
        int b = mgrp * 32 + mt * 16 + bl;
        int j = jg * 4 + jj;
        const float* gx = Gxi + (size_t)(t * 64 + b) * NG_ + jg * 16;
        float iv = gbuf[mt][bl][ 0 + jj] + gx[ 0 + jj];
        float fv = gbuf[mt][bl][ 4 + jj] + gx[ 4 + jj];
        float gv = gbuf[mt][bl][ 8 + jj] + gx[ 8 + jj];
        float ov = gbuf[mt][bl][12 + jj] + gx[12 + jj];
        float si = 1.f / (1.f + expf(-iv));
        float sf = 1.f / (1.f + expf(-fv));
        float so = 1.f / (1.f + expf(-ov));
        float tg = tanhf(gv);
        size_t cidx = (size_t)b * H_ + j;
        float cn = sf * c[cidx] + si * tg;
        c[cidx] = cn;
        float hn = so * tanhf(cn);
        unsigned short hi, lo; split2(hn, hi, lo);
        hpk_out[cidx] = (unsigned int)hi | ((unsigned int)lo << 16);
        out[((size_t)b * S_ + t) * H_ + j] = hn;
    }
}

// ---------------------------------------------------------------------------
extern "C" void kernel_launch(void* const* d_in, const int* in_sizes, int n_in,
                              void* d_out, int out_size, void* d_ws, size_t ws_size,
                              hipStream_t stream)
{
    // Positional defaults (setup_inputs dict order)...
    const float* feat = (const float*)d_in[0];
    const int*   caps = (const int*)d_in[1];
    const float* Wemb = (const float*)d_in[2];
    const float* bemb = (const float*)d_in[3];
    const float* w_ih = (const float*)d_in[4];
    const float* w_hh = (const float*)d_in[5];
    const float* b_ih = (const float*)d_in[6];
    const float* b_hh = (const float*)d_in[7];
    const float* h0   = (const float*)d_in[8];
    const float* c0   = (const float*)d_in[9];
    int nbias = 0, nstate = 0;
    for (int i = 0; i < n_in; ++i) {
        switch (in_sizes[i]) {
            case 64 * 512:        feat = (const float*)d_in[i]; break;
            case 64 * 32:         caps = (const int*)d_in[i];   break;
            case 512 * 32000:     Wemb = (const float*)d_in[i]; break;
            case 512:             bemb = (const float*)d_in[i]; break;
            case 4096 * 512:      w_ih = (const float*)d_in[i]; break;
            case 4096 * 1024:     w_hh = (const float*)d_in[i]; break;
            case 4096:
                if (nbias++ == 0) b_ih = (const float*)d_in[i];
                else              b_hh = (const float*)d_in[i];
                break;
            case 64 * 1024:
                if (nstate++ == 0) h0 = (const float*)d_in[i];
                else               c0 = (const float*)d_in[i];
                break;
            default: break;
        }
    }
    float* out = (float*)d_out;

    // workspace layout (~73 MB total)
    char* ws = (char*)d_ws;
    unsigned short* Xhi  = (unsigned short*)ws; ws += (size_t)2112 * 512 * 2;
    unsigned short* Xlo  = (unsigned short*)ws; ws += (size_t)2112 * 512 * 2;
    float* Gxi           = (float*)ws;          ws += (size_t)2112 * NG_ * 4;   // 34.6MB
    unsigned int* hseq   = (unsigned int*)ws;   ws += (size_t)(S_ + 1) * HB_ * 4; // 8.9MB
    float* cbuf          = (float*)ws;          ws += (size_t)B_ * H_ * 4;
    float* bsum          = (float*)ws;          ws += (size_t)4096 * 4;
    unsigned int* flags  = (unsigned int*)ws;   ws += (size_t)512 * 32 * 4;
    unsigned int* gen    = (unsigned int*)ws;   ws += (size_t)2 * 64 * 32 * 4;  // 64 copies/group
    unsigned short* Wihhi = (unsigned short*)ws; ws += (size_t)4096 * 512 * 2;
    unsigned short* Wihlo = (unsigned short*)ws; ws += (size_t)4096 * 512 * 2;
    unsigned short* Whhhi = (unsigned short*)ws; ws += (size_t)4096 * 1024 * 2;
    unsigned short* Whhlo = (unsigned short*)ws; ws += (size_t)4096 * 1024 * 2;
    size_t needed = (size_t)(ws - (char*)d_ws);
    bool presplit = ws_size >= needed;

    build_x<<<2112, 512, 0, stream>>>(feat, caps, Wemb, bemb, Xhi, Xlo);
    init_state<<<256, 256, 0, stream>>>(h0, c0, hseq, cbuf, flags, gen);
    bias_sum<<<16, 256, 0, stream>>>(b_ih, b_hh, bsum);
    if (presplit) {
        split_w<<<2048, 256, 0, stream>>>(w_ih, Wihhi, Wihlo, (4096 * 512) / 4);
        split_w<<<2048, 256, 0, stream>>>(w_hh, Whhhi, Whhlo, (4096 * 1024) / 4);
        gx_gemm<true><<<66 * 256, 256, 0, stream>>>(Xhi, Xlo, Wihhi, Wihlo,
                                                    w_ih, bsum, Gxi);
    } else {
        gx_gemm<false><<<66 * 256, 256, 0, stream>>>(Xhi, Xlo, Wihhi, Wihlo,
                                                     w_ih, bsum, Gxi);
    }

    // --- persistent cooperative path ---
    void* args[] = {
        (void*)&Gxi,
        (void*)&Whhhi, (void*)&Whhlo, (void*)&w_hh,
        (void*)&hseq, (void*)&cbuf, (void*)&out,
        (void*)&flags, (void*)&gen
    };
    const void* pk = presplit ? (const void*)lstm_persist<true>
                              : (const void*)lstm_persist<false>;
    hipError_t err = hipLaunchCooperativeKernel(pk, dim3(512), dim3(256),
                                                args, 0, stream);
    if (err != hipSuccess) {
        (void)hipGetLastError();   // clear sticky error, fall back
        for (int t = 0; t < S_; ++t) {
            const unsigned int* hin = hseq + (size_t)t * HB_;
            unsigned int*      hout = hseq + (size_t)(t + 1) * HB_;
            if (presplit) {
                lstm_step<true><<<512, 256, 0, stream>>>(
                    Gxi, Whhhi, Whhlo, w_hh, hin, cbuf, hout, out, t);
            } else {
                lstm_step<false><<<512, 256, 0, stream>>>(
                    Gxi, Whhhi, Whhlo, w_hh, hin, cbuf, hout, out, t);
            }
        }
    }
}

// Round 9
// 648.435 us; speedup vs baseline: 5.6484x; 1.0729x over previous
//
#include <hip/hip_runtime.h>
#include <hip/hip_bf16.h>

// Problem constants
#define B_   64
#define T_   32
#define S_   33      // T+1 LSTM steps
#define V_   32000
#define E_   512
#define H_   1024
#define HB_  (B_ * H_)   // one h buffer, in uints (packed hi|lo)
#define NG_  4096        // 4 gates * H

typedef __attribute__((ext_vector_type(8))) short  bf16x8;
typedef __attribute__((ext_vector_type(4))) float  f32x4;

// Split fp32 into hi/lo bf16 pair: x ~= hi + lo  (error ~2^-16 rel)
__device__ inline void split2(float x, unsigned short& hi, unsigned short& lo) {
    __hip_bfloat16 h = __float2bfloat16(x);
    float r = x - __bfloat162float(h);
    __hip_bfloat16 l = __float2bfloat16(r);
    hi = *reinterpret_cast<unsigned short*>(&h);
    lo = *reinterpret_cast<unsigned short*>(&l);
}

// Load 8 contiguous fp32 and split into hi/lo bf16x8 fragments.
__device__ inline void load_f32x8_hilo(const float* __restrict__ p,
                                       bf16x8& hi, bf16x8& lo) {
    const float4* q = reinterpret_cast<const float4*>(p);
    float4 v0 = q[0], v1 = q[1];
    float f[8] = {v0.x, v0.y, v0.z, v0.w, v1.x, v1.y, v1.z, v1.w};
#pragma unroll
    for (int j = 0; j < 8; ++j) {
        unsigned short h, l; split2(f[j], h, l);
        hi[j] = (short)h; lo[j] = (short)l;
    }
}

// Load 8 packed-h uints (hi | lo<<16) with NORMAL cached loads and unpack.
// Safe: hseq buffers are write-once (r6-verified).
__device__ inline void load_hpk8(const unsigned int* __restrict__ p,
                                 bf16x8& hi, bf16x8& lo) {
    uint4 v0 = *reinterpret_cast<const uint4*>(p);
    uint4 v1 = *reinterpret_cast<const uint4*>(p + 4);
    unsigned int w[8] = {v0.x, v0.y, v0.z, v0.w, v1.x, v1.y, v1.z, v1.w};
#pragma unroll
    for (int j = 0; j < 8; ++j) {
        hi[j] = (short)(w[j] & 0xffffu);
        lo[j] = (short)(w[j] >> 16);
    }
}

// ---------------------------------------------------------------------------
// Kernel 1: build X[t*64+b, e]  (time-major) as hi/lo bf16.
// ---------------------------------------------------------------------------
__global__ __launch_bounds__(512) void build_x(
    const float* __restrict__ feat,   // [B,E]
    const int*   __restrict__ caps,   // [B,T] int32
    const float* __restrict__ Wemb,   // [E,V]
    const float* __restrict__ bemb,   // [E]
    unsigned short* __restrict__ Xhi,
    unsigned short* __restrict__ Xlo)
{
    int row = blockIdx.x;          // t*64 + b
    int t = row >> 6, b = row & 63;
    int e = threadIdx.x;
    float x;
    if (t == 0) {
        x = feat[b * E_ + e];
    } else {
        int cap = caps[b * T_ + (t - 1)];
        x = Wemb[(size_t)e * V_ + cap] + bemb[e];
    }
    unsigned short hi, lo; split2(x, hi, lo);
    Xhi[(size_t)row * E_ + e] = hi;
    Xlo[(size_t)row * E_ + e] = lo;
}

// ---------------------------------------------------------------------------
// Kernel 2: init LSTM state + zero barrier flags / distributed gen copies.
// ---------------------------------------------------------------------------
__global__ __launch_bounds__(256) void init_state(
    const float* __restrict__ h0,
    const float* __restrict__ c0,
    unsigned int* __restrict__ hseq0,
    float* __restrict__ c,
    unsigned int* __restrict__ flags,   // [512 * 32]
    unsigned int* __restrict__ gen)     // [2*64*32]
{
    int idx = blockIdx.x * 256 + threadIdx.x;
    if (idx < 512 * 32)    flags[idx] = 0u;
    if (idx < 2 * 64 * 32) gen[idx]   = 0u;
    unsigned short hi, lo; split2(h0[idx], hi, lo);
    hseq0[idx] = (unsigned int)hi | ((unsigned int)lo << 16);
    c[idx]   = c0[idx];
}

// Kernel 2c: bsum = b_ih + b_hh  (4096 elems)
__global__ __launch_bounds__(256) void bias_sum(
    const float* __restrict__ a, const float* __restrict__ b,
    float* __restrict__ s)
{
    int i = blockIdx.x * 256 + threadIdx.x;
    s[i] = a[i] + b[i];
}

// ---------------------------------------------------------------------------
// Kernel 2d (r9 restructure): Gxi = X @ w_ih^T + bsum with W REUSE.
// grid 512 = (jg 0..255) x (mhalf 0..1); 4 waves split K (4 x 128).
// Each block: preload+split its 16 gate-interleaved W rows' K-fragments into
// registers ("+v"-pinned so the allocator can't rematerialize the loads),
// then loop 33 m-tiles of 32 rows. W traffic 554MB -> 8.4MB vs r7/r8.
// Output gate-interleaved: Gxi[row][jg*16 + g*4 + jj], n = g*1024 + jg*4 + jj.
// ---------------------------------------------------------------------------
__global__ __launch_bounds__(256, 2) void gx_gemm(
    const unsigned short* __restrict__ Xhi,    // [2112, 512]
    const unsigned short* __restrict__ Xlo,
    const float* __restrict__ w_ih,            // [4096, 512] fp32
    const float* __restrict__ bsum,            // [4096]
    float* __restrict__ Gxi)                   // [2112, 4096] interleaved
{
    int bx    = blockIdx.x;
    int jg    = bx & 255;
    int mhalf = bx >> 8;
    int wave  = threadIdx.x >> 6;
    int lane  = threadIdx.x & 63;
    int lm    = lane & 15;
    int kq    = (lane >> 4) * 8;
    int tid   = threadIdx.x;
    int nrow  = (lm >> 2) * H_ + jg * 4 + (lm & 3);
    int k0    = wave * 128;

    // preload + in-kernel split of W (m-invariant); pin in registers
    bf16x8 wh[4], wl[4];
    {
        const float* Bf = w_ih + (size_t)nrow * E_ + k0 + kq;
#pragma unroll
        for (int i = 0; i < 4; ++i) load_f32x8_hilo(Bf + i * 32, wh[i], wl[i]);
    }
#pragma unroll
    for (int i = 0; i < 4; ++i)
        asm volatile("" : "+v"(wh[i]), "+v"(wl[i]));

    // hoist bias: thread writes (mt=0,1) at fixed (row,col) -> one bias value
    int colt = tid & 15;
    float bias0 = bsum[(colt >> 2) * H_ + jg * 4 + (colt & 3)];

    __shared__ float pbuf[4][2][16][17];
    int rbase = (lane >> 4) * 4;   // C/D: col=lane&15, row=(lane>>4)*4+r (verified)

    for (int mt2 = 0; mt2 < 33; ++mt2) {
        int m0 = mhalf * 1056 + mt2 * 32;

        f32x4 acc0 = f32x4{0.f, 0.f, 0.f, 0.f};
        f32x4 acc1 = f32x4{0.f, 0.f, 0.f, 0.f};
#pragma unroll
        for (int i = 0; i < 4; ++i) {
            int k = k0 + i * 32 + kq;
            bf16x8 a0h = *reinterpret_cast<const bf16x8*>(Xhi + (size_t)(m0 + lm) * E_ + k);
            bf16x8 a0l = *reinterpret_cast<const bf16x8*>(Xlo + (size_t)(m0 + lm) * E_ + k);
            bf16x8 a1h = *reinterpret_cast<const bf16x8*>(Xhi + (size_t)(m0 + 16 + lm) * E_ + k);
            bf16x8 a1l = *reinterpret_cast<const bf16x8*>(Xlo + (size_t)(m0 + 16 + lm) * E_ + k);
            acc0 = __builtin_amdgcn_mfma_f32_16x16x32_bf16(a0h, wh[i], acc0, 0, 0, 0);
            acc0 = __builtin_amdgcn_mfma_f32_16x16x32_bf16(a0l, wh[i], acc0, 0, 0, 0);
            acc0 = __builtin_amdgcn_mfma_f32_16x16x32_bf16(a0h, wl[i], acc0, 0, 0, 0);
            acc1 = __builtin_amdgcn_mfma_f32_16x16x32_bf16(a1h, wh[i], acc1, 0, 0, 0);
            acc1 = __builtin_amdgcn_mfma_f32_16x16x32_bf16(a1l, wh[i], acc1, 0, 0, 0);
            acc1 = __builtin_amdgcn_mfma_f32_16x16x32_bf16(a1h, wl[i], acc1, 0, 0, 0);
        }

#pragma unroll
        for (int r = 0; r < 4; ++r) {
            pbuf[wave][0][rbase + r][lm] = acc0[r];
            pbuf[wave][1][rbase + r][lm] = acc1[r];
        }
        __syncthreads();

        for (int idx = tid; idx < 512; idx += 256) {
            int mt = idx >> 8;
            int row = (idx & 255) >> 4, col = idx & 15;
            float v = pbuf[0][mt][row][col] + pbuf[1][mt][row][col]
                    + pbuf[2][mt][row][col] + pbuf[3][mt][row][col];
            Gxi[(size_t)(m0 + mt * 16 + row) * NG_ + jg * 16 + col] = v + bias0;
        }
        __syncthreads();
    }
}

// ---------------------------------------------------------------------------
// Kernel 3a (persistent, cooperative): ALL 33 LSTM steps, h-GEMM only.
// r8 structure + fixes per r8 post-mortem:
//  (1) w_hh preload (split in-kernel from fp32 -- split_w kernel deleted) is
//      PINNED with asm "+v": the asm defines the values, so the allocator
//      cannot rematerialize the loads inside the t-loop (r8: VGPR=76 proved
//      it had). Expect VGPR ~180-230.
//  (2) Gxi prefetch moved INTO the barrier window (after drain-sync, before
//      the spin) -> its IC latency hides under the barrier.
// Barrier/visibility identical to r6/r7/r8 (verified).
// ---------------------------------------------------------------------------
__global__ __launch_bounds__(256, 2) void lstm_persist(
    const float* __restrict__ Gxi,             // [2112, 4096] interleaved
    const float* __restrict__ w_hh,            // [4096, 1024] fp32
    unsigned int* __restrict__ hseq,           // [34][64*1024] write-once
    float* __restrict__ c,                     // [64, 1024] (block-local)
    float* __restrict__ out,                   // [B][S][H] fp32
    unsigned int* __restrict__ flags,          // [512 * 32]
    unsigned int* __restrict__ gen)            // [2][64][32] copies
{
    int bx   = blockIdx.x;
    int jg   = bx & 255;          // 4-col group within H
    int mgrp = bx >> 8;           // 0..1 : 32-batch group
    int wave = threadIdx.x >> 6;  // 0..3 : K-chunk of 256
    int lane = threadIdx.x & 63;
    int lm   = lane & 15;
    int kq   = (lane >> 4) * 8;
    int tid  = threadIdx.x;

    int gbase    = bx & 256;
    bool checker = (bx == gbase);
    unsigned int* mygen = gen + ((size_t)mgrp * 64 + ((bx & 255) >> 2)) * 32;

    int nrow = (lm >> 2) * H_ + jg * 4 + (lm & 3);
    int k0   = wave * 256;

    // ---- (1) preload + split w_hh; pin in registers ----
    bf16x8 wh[8], wl[8];
    {
        const float* Bf = w_hh + (size_t)nrow * H_ + k0 + kq;
#pragma unroll
        for (int i = 0; i < 8; ++i) load_f32x8_hilo(Bf + i * 32, wh[i], wl[i]);
    }
#pragma unroll
    for (int i = 0; i < 8; ++i)
        asm volatile("" : "+v"(wh[i]), "+v"(wl[i]));

    __shared__ float pbuf[4][2][16][17];
    __shared__ float gbuf[2][16][17];
    int rbase = (lane >> 4) * 4;

    // Gxi tile prefetch state (held in regs across the barrier)
    float gx_i = 0.f, gx_f = 0.f, gx_g = 0.f, gx_o = 0.f;
    int pmt = tid >> 6, pbl = (tid >> 2) & 15, pjj = tid & 3;
    int pb  = mgrp * 32 + pmt * 16 + pbl;     // valid when tid < 128
    auto prefetch_gx = [&](int t) {
        if (tid < 128) {
            const float* gx = Gxi + (size_t)(t * 64 + pb) * NG_ + jg * 16;
            gx_i = gx[ 0 + pjj];
            gx_f = gx[ 4 + pjj];
            gx_g = gx[ 8 + pjj];
            gx_o = gx[12 + pjj];
        }
    };
    prefetch_gx(0);

    for (int t = 0; t < S_; ++t) {
        const unsigned int* hpk_in = hseq + (size_t)t * HB_;
        unsigned int*      hpk_out = hseq + (size_t)(t + 1) * HB_;
        const unsigned int* hrow0 = hpk_in + (size_t)(mgrp * 32 + lm) * H_ + k0 + kq;
        const unsigned int* hrow1 = hpk_in + (size_t)(mgrp * 32 + 16 + lm) * H_ + k0 + kq;

        f32x4 acc0 = f32x4{0.f, 0.f, 0.f, 0.f};
        f32x4 acc1 = f32x4{0.f, 0.f, 0.f, 0.f};

#pragma unroll
        for (int i = 0; i < 8; ++i) {
            bf16x8 a0h, a0l, a1h, a1l;
            load_hpk8(hrow0 + i * 32, a0h, a0l);
            load_hpk8(hrow1 + i * 32, a1h, a1l);
            acc0 = __builtin_amdgcn_mfma_f32_16x16x32_bf16(a0h, wh[i], acc0, 0, 0, 0);
            acc0 = __builtin_amdgcn_mfma_f32_16x16x32_bf16(a0l, wh[i], acc0, 0, 0, 0);
            acc0 = __builtin_amdgcn_mfma_f32_16x16x32_bf16(a0h, wl[i], acc0, 0, 0, 0);
            acc1 = __builtin_amdgcn_mfma_f32_16x16x32_bf16(a1h, wh[i], acc1, 0, 0, 0);
            acc1 = __builtin_amdgcn_mfma_f32_16x16x32_bf16(a1l, wh[i], acc1, 0, 0, 0);
            acc1 = __builtin_amdgcn_mfma_f32_16x16x32_bf16(a1h, wl[i], acc1, 0, 0, 0);
        }

#pragma unroll
        for (int r = 0; r < 4; ++r) {
            pbuf[wave][0][rbase + r][lm] = acc0[r];
            pbuf[wave][1][rbase + r][lm] = acc1[r];
        }
        __syncthreads();

        for (int idx = tid; idx < 512; idx += 256) {
            int mt = idx >> 8, rc = idx & 255;
            int row = rc >> 4, col = rc & 15;
            gbuf[mt][row][col] = pbuf[0][mt][row][col] + pbuf[1][mt][row][col]
                               + pbuf[2][mt][row][col] + pbuf[3][mt][row][col];
        }
        __syncthreads();

        // fused pointwise: gates = prefetched Gxi + h-GEMM; 128 outputs
        if (tid < 128) {
            int b = pb;
            int j = jg * 4 + pjj;
            float iv = gbuf[pmt][pbl][ 0 + pjj] + gx_i;
            float fv = gbuf[pmt][pbl][ 4 + pjj] + gx_f;
            float gv = gbuf[pmt][pbl][ 8 + pjj] + gx_g;
            float ov = gbuf[pmt][pbl][12 + pjj] + gx_o;
            float si = 1.f / (1.f + expf(-iv));
            float sf = 1.f / (1.f + expf(-fv));
            float so = 1.f / (1.f + expf(-ov));
            float tg = tanhf(gv);
            size_t cidx = (size_t)b * H_ + j;
            float cn = sf * c[cidx] + si * tg;
            c[cidx] = cn;
            float hn = so * tanhf(cn);
            unsigned short hi, lo; split2(hn, hi, lo);
            __hip_atomic_store(&hpk_out[cidx],
                               (unsigned int)hi | ((unsigned int)lo << 16),
                               __ATOMIC_RELAXED, __HIP_MEMORY_SCOPE_AGENT);
            out[((size_t)b * S_ + t) * H_ + j] = hn;
        }

        // ---- barrier with (2) overlapped Gxi prefetch ----
        __syncthreads();   // drains vmcnt(0) on every wave -> h stores visible
        unsigned int target = (unsigned int)(t + 1);
        if (!checker) {
            if (tid == 0) {
                __hip_atomic_store(&flags[(size_t)bx * 32], target,
                                   __ATOMIC_RELAXED, __HIP_MEMORY_SCOPE_AGENT);
            }
            if (t + 1 < S_) prefetch_gx(t + 1);   // latency hides under spin
            if (tid == 0) {
                while (__hip_atomic_load(mygen, __ATOMIC_RELAXED,
                                         __HIP_MEMORY_SCOPE_AGENT) < target) {
                    __builtin_amdgcn_s_sleep(2);
                }
            }
        } else {
            if (t + 1 < S_) prefetch_gx(t + 1);
            int fi = gbase + 1 + tid;          // valid for tid < 255
            bool need = (tid < 255);
            for (;;) {
                int ok = 1;
                if (need) {
                    ok = (__hip_atomic_load(&flags[(size_t)fi * 32],
                                            __ATOMIC_RELAXED,
                                            __HIP_MEMORY_SCOPE_AGENT) >= target);
                }
                if (__syncthreads_and(ok)) break;
                __builtin_amdgcn_s_sleep(2);
            }
            if (tid < 64) {
                __hip_atomic_store(gen + ((size_t)mgrp * 64 + tid) * 32, target,
                                   __ATOMIC_RELAXED, __HIP_MEMORY_SCOPE_AGENT);
            }
        }
        __syncthreads();
    }
}

// ---------------------------------------------------------------------------
// Kernel 3b: single-step fallback if cooperative launch is unavailable
// (fp32 weights, per-use split -- bit-identical math; r7-verified pattern).
// ---------------------------------------------------------------------------
__global__ __launch_bounds__(256) void lstm_step(
    const float* __restrict__ Gxi,
    const float* __restrict__ w_hh,
    const unsigned int* __restrict__ hpk_in,
    float* __restrict__ c,
    unsigned int* __restrict__ hpk_out,
    float* __restrict__ out,
    int t)
{
    int bx   = blockIdx.x;
    int jg   = bx & 255;
    int mgrp = bx >> 8;
    int wave = threadIdx.x >> 6;
    int lane = threadIdx.x & 63;
    int lm   = lane & 15;
    int kq   = (lane >> 4) * 8;
    int tid  = threadIdx.x;
    int nrow = (lm >> 2) * H_ + jg * 4 + (lm & 3);
    int k0   = wave * 256;

    const float* Bf = w_hh + (size_t)nrow * H_;
    const unsigned int* hrow0 = hpk_in + (size_t)(mgrp * 32 + lm) * H_;
    const unsigned int* hrow1 = hpk_in + (size_t)(mgrp * 32 + 16 + lm) * H_;

    f32x4 acc0 = f32x4{0.f, 0.f, 0.f, 0.f};
    f32x4 acc1 = f32x4{0.f, 0.f, 0.f, 0.f};

#pragma unroll
    for (int kk = 0; kk < 256; kk += 32) {
        int k = k0 + kk + kq;
        bf16x8 bhi, blo;
        load_f32x8_hilo(Bf + k, bhi, blo);
        bf16x8 a0h, a0l, a1h, a1l;
        load_hpk8(hrow0 + k, a0h, a0l);
        load_hpk8(hrow1 + k, a1h, a1l);
        acc0 = __builtin_amdgcn_mfma_f32_16x16x32_bf16(a0h, bhi, acc0, 0, 0, 0);
        acc0 = __builtin_amdgcn_mfma_f32_16x16x32_bf16(a0l, bhi, acc0, 0, 0, 0);
        acc0 = __builtin_amdgcn_mfma_f32_16x16x32_bf16(a0h, blo, acc0, 0, 0, 0);
        acc1 = __builtin_amdgcn_mfma_f32_16x16x32_bf16(a1h, bhi, acc1, 0, 0, 0);
        acc1 = __builtin_amdgcn_mfma_f32_16x16x32_bf16(a1l, bhi, acc1, 0, 0, 0);
        acc1 = __builtin_amdgcn_mfma_f32_16x16x32_bf16(a1h, blo, acc1, 0, 0, 0);
    }

    __shared__ float pbuf[4][2][16][17];
    __shared__ float gbuf[2][16][17];
    int rbase = (lane >> 4) * 4;
#pragma unroll
    for (int r = 0; r < 4; ++r) {
        pbuf[wave][0][rbase + r][lm] = acc0[r];
        pbuf[wave][1][rbase + r][lm] = acc1[r];
    }
    __syncthreads();

    for (int idx = tid; idx < 512; idx += 256) {
        int mt = idx >> 8, rc = idx & 255;
        int row = rc >> 4, col = rc & 15;
        gbuf[mt][row][col] = pbuf[0][mt][row][col] + pbuf[1][mt][row][col]
                           + pbuf[2][mt][row][col] + pbuf[3][mt][row][col];
    }
    __syncthreads();

    if (tid < 128) {
        int mt = tid >> 6, bl = (tid >> 2) & 15, jj = tid & 3;
        int b = mgrp * 32 + mt * 16 + bl;
        int j = jg * 4 + jj;
        const float* gx = Gxi + (size_t)(t * 64 + b) * NG_ + jg * 16;
        float iv = gbuf[mt][bl][ 0 + jj] + gx[ 0 + jj];
        float fv = gbuf[mt][bl][ 4 + jj] + gx[ 4 + jj];
        float gv = gbuf[mt][bl][ 8 + jj] + gx[ 8 + jj];
        float ov = gbuf[mt][bl][12 + jj] + gx[12 + jj];
        float si = 1.f / (1.f + expf(-iv));
        float sf = 1.f / (1.f + expf(-fv));
        float so = 1.f / (1.f + expf(-ov));
        float tg = tanhf(gv);
        size_t cidx = (size_t)b * H_ + j;
        float cn = sf * c[cidx] + si * tg;
        c[cidx] = cn;
        float hn = so * tanhf(cn);
        unsigned short hi, lo; split2(hn, hi, lo);
        hpk_out[cidx] = (unsigned int)hi | ((unsigned int)lo << 16);
        out[((size_t)b * S_ + t) * H_ + j] = hn;
    }
}

// ---------------------------------------------------------------------------
extern "C" void kernel_launch(void* const* d_in, const int* in_sizes, int n_in,
                              void* d_out, int out_size, void* d_ws, size_t ws_size,
                              hipStream_t stream)
{
    // Positional defaults (setup_inputs dict order)...
    const float* feat = (const float*)d_in[0];
    const int*   caps = (const int*)d_in[1];
    const float* Wemb = (const float*)d_in[2];
    const float* bemb = (const float*)d_in[3];
    const float* w_ih = (const float*)d_in[4];
    const float* w_hh = (const float*)d_in[5];
    const float* b_ih = (const float*)d_in[6];
    const float* b_hh = (const float*)d_in[7];
    const float* h0   = (const float*)d_in[8];
    const float* c0   = (const float*)d_in[9];
    int nbias = 0, nstate = 0;
    for (int i = 0; i < n_in; ++i) {
        switch (in_sizes[i]) {
            case 64 * 512:        feat = (const float*)d_in[i]; break;
            case 64 * 32:         caps = (const int*)d_in[i];   break;
            case 512 * 32000:     Wemb = (const float*)d_in[i]; break;
            case 512:             bemb = (const float*)d_in[i]; break;
            case 4096 * 512:      w_ih = (const float*)d_in[i]; break;
            case 4096 * 1024:     w_hh = (const float*)d_in[i]; break;
            case 4096:
                if (nbias++ == 0) b_ih = (const float*)d_in[i];
                else              b_hh = (const float*)d_in[i];
                break;
            case 64 * 1024:
                if (nstate++ == 0) h0 = (const float*)d_in[i];
                else               c0 = (const float*)d_in[i];
                break;
            default: break;
        }
    }
    float* out = (float*)d_out;

    // workspace layout (~49 MB; split-weight buffers removed in r9)
    char* ws = (char*)d_ws;
    unsigned short* Xhi  = (unsigned short*)ws; ws += (size_t)2112 * 512 * 2;
    unsigned short* Xlo  = (unsigned short*)ws; ws += (size_t)2112 * 512 * 2;
    float* Gxi           = (float*)ws;          ws += (size_t)2112 * NG_ * 4;     // 34.6MB
    unsigned int* hseq   = (unsigned int*)ws;   ws += (size_t)(S_ + 1) * HB_ * 4; // 8.9MB
    float* cbuf          = (float*)ws;          ws += (size_t)B_ * H_ * 4;
    float* bsum          = (float*)ws;          ws += (size_t)4096 * 4;
    unsigned int* flags  = (unsigned int*)ws;   ws += (size_t)512 * 32 * 4;
    unsigned int* gen    = (unsigned int*)ws;   ws += (size_t)2 * 64 * 32 * 4;

    build_x<<<2112, 512, 0, stream>>>(feat, caps, Wemb, bemb, Xhi, Xlo);
    init_state<<<256, 256, 0, stream>>>(h0, c0, hseq, cbuf, flags, gen);
    bias_sum<<<16, 256, 0, stream>>>(b_ih, b_hh, bsum);
    gx_gemm<<<512, 256, 0, stream>>>(Xhi, Xlo, w_ih, bsum, Gxi);

    // --- persistent cooperative path ---
    void* args[] = {
        (void*)&Gxi, (void*)&w_hh,
        (void*)&hseq, (void*)&cbuf, (void*)&out,
        (void*)&flags, (void*)&gen
    };
    hipError_t err = hipLaunchCooperativeKernel((const void*)lstm_persist,
                                                dim3(512), dim3(256),
                                                args, 0, stream);
    if (err != hipSuccess) {
        (void)hipGetLastError();   // clear sticky error, fall back
        for (int t = 0; t < S_; ++t) {
            const unsigned int* hin = hseq + (size_t)t * HB_;
            unsigned int*      hout = hseq + (size_t)(t + 1) * HB_;
            lstm_step<<<512, 256, 0, stream>>>(
                Gxi, w_hh, hin, cbuf, hout, out, t);
        }
    }
}